// Round 8
// baseline (140.190 us; speedup 1.0000x reference)
//
#include <hip/hip_runtime.h>
#include <math.h>

// Problem constants
#define NCODES 2048
#define CDIM   256
#define SPAT   4096            // T*H*W
#define NTOK   32768
#define XSTR   260             // fp32 Xs row stride in k_epi (1040B, 16B-aligned)
#define EPI_TOK 32             // tokens per k_epi block (33.3KB Xs -> 4 blocks/CU, full-line IO)

// k_main geometry: 512 blocks = 256 token-groups(128 tok) x 2 code-halves
#define ETILE    32            // codes per staged tile
#define HALFCODE 1024
#define NTILES   (HALFCODE / ETILE)   // 32

typedef _Float16 half8  __attribute__((ext_vector_type(8)));
typedef float    f32x4  __attribute__((ext_vector_type(4)));

// ws layout (float offsets)
#define WS_ENORM  0         // 2048
#define WS_COUNTS 2048      // 2048
#define WS_LOSS   4096
#define WS_N      4097
#define WS_ESUM   4100      // 2048*256 floats (memset with counts: [2048, 528388))
#define WS_IDX    528388    // int[32768] token -> code
#define WS_OFF    561156    // int[2048] exclusive-scan offsets
#define WS_CUR    563204    // int[2048] scatter cursors
#define WS_SORT   565252    // int[32768] token ids sorted by code
#define WS_SCODE  598020    // int[32768] code per sorted slot
#define WS_CAND   630788    // 16B-aligned; 32768 tok x 8 ushort
#define WS_E16    761860    // 16B-aligned; fp16 swizzled codebook image (1 MB)
#define WS_XH     1024004   // 16B-aligned; fp16 token-major z image (16.8 MB)

// d_out layout (float offsets)
#define O_QUANT 0
#define O_ENC   8388608
#define O_LOSS  8421376
#define O_PERP  8421377
#define O_EMB   8421378
#define O_NN    8945666
#define O_ZAVG  8947714

__device__ inline void gl_lds16(const void* g, void* l) {
    __builtin_amdgcn_global_load_lds(
        (const __attribute__((address_space(1))) void*)g,
        (__attribute__((address_space(3))) void*)l, 16, 0, 0);
}

__device__ inline unsigned umn(unsigned a, unsigned b) { return a < b ? a : b; }
__device__ inline unsigned umx(unsigned a, unsigned b) { return a > b ? a : b; }
__device__ inline unsigned shflx16(unsigned v, int off) {
    return (unsigned)__shfl_xor((int)v, off, 16);
}

// ---- codebook prep: fp16 swizzled LDS-image + row norms (once per call) ----
__global__ void k_ecvt(const float* __restrict__ emb, float* __restrict__ ws) {
    const int tid  = threadIdx.x;
    const int code = (blockIdx.x << 3) + (tid >> 5);   // 8 codes/block
    const int cg   = tid & 31;                         // c = cg*8
    const float* src = emb + (size_t)code * CDIM + (cg << 3);
    const float4 f0 = *(const float4*)src;
    const float4 f1 = *(const float4*)(src + 4);
    half8 h = { (_Float16)f0.x, (_Float16)f0.y, (_Float16)f0.z, (_Float16)f0.w,
                (_Float16)f1.x, (_Float16)f1.y, (_Float16)f1.z, (_Float16)f1.w };
    char* dst = (char*)(ws + WS_E16) + (size_t)code * 512 + ((cg ^ (code & 7)) << 4);
    *(half8*)dst = h;
    float s = f0.x * f0.x + f0.y * f0.y + f0.z * f0.z + f0.w * f0.w
            + f1.x * f1.x + f1.y * f1.y + f1.z * f1.z + f1.w * f1.w;
#pragma unroll
    for (int off = 16; off; off >>= 1) s += __shfl_down(s, off, 32);
    if (cg == 0) ws[WS_ENORM + code] = s;   // exact norm (k_epi re-rank uses it)
}

// ---------------- MFMA distance + top-4-per-half candidate kernel ----------------
// 512 blocks x 256 threads (4 waves). Block = (128 tokens) x (code-half of 1024).
// XCD pair-swizzle: both half-blocks of a token group land on one XCD.
// 3-deep LDS pipeline with counted vmcnt + raw s_barrier (T3/T4): tile t
// computes from buf[t%3] while E(t+1) is landed and E(t+2) is in flight --
// the compiler's vmcnt(0)-before-__syncthreads drain is eliminated.
// e-norm loads are issued OLDEST in each tile so consuming them (vmcnt<=4)
// never drains the prefetch.
__global__ __launch_bounds__(256, 3) void k_main(
    const float* __restrict__ z, float* __restrict__ ws)
{
    __shared__ half8 Es8[3][ETILE][32];   // 48 KB, 3-deep

    const int tid = threadIdx.x;
    const int raw = blockIdx.x;
    const int xcd = raw & 7, sub = raw >> 3;   // 512 = 8 XCDs x 64 subs
    const int tb  = xcd * 32 + (sub >> 1);     // token group 0..255
    const int ch  = sub & 1;                   // code half
    const int b   = tb >> 5;
    const int s0  = (tb & 31) * 128;
    const float* zb = z + (size_t)b * CDIM * SPAT + s0;
    const char* e16g = (const char*)(ws + WS_E16) + (size_t)ch * HALFCODE * 512;

    const int l  = tid & 63, w = tid >> 6;
    const int lr = l & 15, lg = l >> 4;

#define STAGE(tileidx, bufidx) do {                                         \
        const char* src_ = e16g + (size_t)(tileidx) * (ETILE * 512);        \
        char* dst_ = (char*)&Es8[bufidx][0][0];                             \
        _Pragma("unroll")                                                   \
        for (int q_ = 0; q_ < 4; ++q_) {                                    \
            const int off_ = ((q_ << 2) + w) << 10;                         \
            gl_lds16(src_ + off_ + (l << 4), dst_ + off_);                  \
        } } while (0)

    // ---- stage E(0) ----
    STAGE(0, 0);

    // ---- A-frags: 2 sets x 8 ks, global -> registers (overlaps E(0) DMA) ----
    half8 a[2][8];
#pragma unroll
    for (int as = 0; as < 2; ++as)
#pragma unroll
    for (int ks = 0; ks < 8; ++ks) {
        float v[8];
#pragma unroll
        for (int e = 0; e < 8; ++e)
            v[e] = zb[(size_t)(ks * 32 + lg * 8 + e) * SPAT + (w * 32 + as * 16 + lr)];
        half8 h = { (_Float16)v[0], (_Float16)v[1], (_Float16)v[2], (_Float16)v[3],
                    (_Float16)v[4], (_Float16)v[5], (_Float16)v[6], (_Float16)v[7] };
        a[as][ks] = h;
    }

    // ---- Xh dump (ch==0 blocks only): token-major fp16 rows from A-frags ----
    if (ch == 0) {
        _Float16* xh = (_Float16*)(ws + WS_XH);
#pragma unroll
        for (int as = 0; as < 2; ++as) {
            _Float16* xr = xh + (size_t)(b * SPAT + s0 + w * 32 + as * 16 + lr) * CDIM;
#pragma unroll
            for (int ks = 0; ks < 8; ++ks)
                *(half8*)(xr + ks * 32 + lg * 8) = a[as][ks];
        }
    }

    unsigned kb0[2][4], kb1[2][4];   // top-2 packed keys per (A-set, r) slot
#pragma unroll
    for (int as = 0; as < 2; ++as)
#pragma unroll
    for (int r = 0; r < 4; ++r) { kb0[as][r] = 0xFFFFFFFFu; kb1[as][r] = 0xFFFFFFFFu; }

    // E(0) landed for all waves; Xh stores drained too.
    asm volatile("s_waitcnt vmcnt(0)" ::: "memory");
    __builtin_amdgcn_s_barrier();
    __builtin_amdgcn_sched_barrier(0);

    // ---- stage E(1): stays in flight across tile 0 ----
    STAGE(1, 1);

    // per-tile compute from buffer bp (en0/en1 pre-loaded by caller)
    auto compute_tile = [&](int bp, int tile, float en0, float en1) {
        f32x4 acc[2][2];
#pragma unroll
        for (int as = 0; as < 2; ++as)
#pragma unroll
        for (int j = 0; j < 2; ++j) acc[as][j] = (f32x4)0.0f;

        half8 bf0[2], bf1[2];
#pragma unroll
        for (int j = 0; j < 2; ++j) {
            const int row = j * 16 + lr;
            bf0[j] = Es8[bp][row][lg ^ (row & 7)];
        }
#pragma unroll
        for (int ks = 0; ks < 8; ++ks) {
            if (ks < 7) {
#pragma unroll
                for (int j = 0; j < 2; ++j) {
                    const int row = j * 16 + lr;
                    if (ks & 1) bf0[j] = Es8[bp][row][((ks + 1) * 4 + lg) ^ (row & 7)];
                    else        bf1[j] = Es8[bp][row][((ks + 1) * 4 + lg) ^ (row & 7)];
                }
            }
            __builtin_amdgcn_s_setprio(1);
#pragma unroll
            for (int as = 0; as < 2; ++as)
#pragma unroll
            for (int j = 0; j < 2; ++j)
                acc[as][j] = __builtin_amdgcn_mfma_f32_16x16x32_f16(
                    a[as][ks], (ks & 1) ? bf1[j] : bf0[j], acc[as][j], 0, 0, 0);
            __builtin_amdgcn_s_setprio(0);
        }

        // fold into per-lane top-2 packed keys
        const float enb0 = en0 + 4096.0f;
        const float enb1 = en1 + 4096.0f;
        const unsigned code0 = (unsigned)(ch * HALFCODE + tile * ETILE + lr);
        const unsigned code1 = code0 + 16u;
#pragma unroll
        for (int as = 0; as < 2; ++as)
#pragma unroll
        for (int r = 0; r < 4; ++r) {
            {
                const float d = fmaf(acc[as][0][r], -2.0f, enb0);
                const unsigned key = (__float_as_uint(d) & 0xFFFFF800u) | code0;
                const unsigned hi = umx(kb0[as][r], key);
                kb0[as][r] = umn(kb0[as][r], key);
                kb1[as][r] = umn(kb1[as][r], hi);
            }
            {
                const float d = fmaf(acc[as][1][r], -2.0f, enb1);
                const unsigned key = (__float_as_uint(d) & 0xFFFFF800u) | code1;
                const unsigned hi = umx(kb0[as][r], key);
                kb0[as][r] = umn(kb0[as][r], key);
                kb1[as][r] = umn(kb1[as][r], hi);
            }
        }
    };

    int p = 0;
    for (int tile = 0; tile < NTILES; ++tile) {
        // e-norm loads FIRST (oldest vmem of this tile): consuming them in the
        // fold needs only vmcnt<=4, never draining the E(t+2) prefetch.
        const float en0 = ws[WS_ENORM + ch * HALFCODE + tile * ETILE + lr];
        const float en1 = ws[WS_ENORM + ch * HALFCODE + tile * ETILE + 16 + lr];

        if (tile + 2 < NTILES) {
            const int p2 = (p + 2 >= 3) ? p - 1 : p + 2;
            STAGE(tile + 2, p2);
        }

        compute_tile(p, tile, en0, en1);

        if (tile + 2 < NTILES) {
            // E(t+1) landed (in-order retire); E(t+2)'s 4 loads stay in flight.
            asm volatile("s_waitcnt vmcnt(4)" ::: "memory");
            __builtin_amdgcn_s_barrier();
            __builtin_amdgcn_sched_barrier(0);
        } else if (tile + 2 == NTILES) {
            // last prefetch (E(31)) must land; nothing else outstanding.
            asm volatile("s_waitcnt vmcnt(0)" ::: "memory");
            __builtin_amdgcn_s_barrier();
            __builtin_amdgcn_sched_barrier(0);
        }
        // tile == NTILES-1: no barrier needed after the last compute.
        p = (p == 2) ? 0 : p + 1;
    }
#undef STAGE

    // ---- 16-lane bitonic merge of sorted-4 key lists -> top-4 per token ----
#pragma unroll
    for (int as = 0; as < 2; ++as)
#pragma unroll
    for (int r = 0; r < 4; ++r) {
        unsigned k0 = kb0[as][r], k1 = kb1[as][r];
        unsigned k2 = 0xFFFFFFFFu, k3 = 0xFFFFFFFFu;
#pragma unroll
        for (int off = 8; off; off >>= 1) {
            const unsigned o0 = shflx16(k0, off);
            const unsigned o1 = shflx16(k1, off);
            const unsigned o2 = shflx16(k2, off);
            const unsigned o3 = shflx16(k3, off);
            // lowest-4 of two ascending 4-lists: min with reversed other -> bitonic
            const unsigned m0 = umn(k0, o3), m1 = umn(k1, o2);
            const unsigned m2 = umn(k2, o1), m3 = umn(k3, o0);
            // sort the bitonic 4-sequence
            const unsigned t0 = umn(m0, m2), t2 = umx(m0, m2);
            const unsigned t1 = umn(m1, m3), t3 = umx(m1, m3);
            k0 = umn(t0, t1); k1 = umx(t0, t1);
            k2 = umn(t2, t3); k3 = umx(t2, t3);
        }
        if (lr == 0) {
            const int tokg = b * SPAT + s0 + w * 32 + as * 16 + lg * 4 + r;
            ushort4 c4;
            c4.x = (unsigned short)(k0 & 2047u);
            c4.y = (unsigned short)(k1 & 2047u);
            c4.z = (unsigned short)(k2 & 2047u);
            c4.w = (unsigned short)(k3 & 2047u);
            *(ushort4*)((unsigned short*)((int*)ws + WS_CAND) + (size_t)tokg * 8 + ch * 4) = c4;
        }
    }
}

// ---------------- exact fp32 re-rank (8 cands) + epilogue ----------------
// 1024 blocks x 256 threads, 32 tokens/block, Xs 33.3KB -> 4 blocks/CU.
// EPI_TOK=32 => 128B full-line z reads and quant writes.
__global__ __launch_bounds__(256, 4) void k_epi(
    const float* __restrict__ z, const float* __restrict__ emb,
    float* __restrict__ ws, float* __restrict__ out)
{
    __shared__ float Xs[EPI_TOK * XSTR];   // 33280 B fp32
    __shared__ int   idxs[EPI_TOK];
    __shared__ float lloss[EPI_TOK];

    const int tid = threadIdx.x, blk = blockIdx.x;
    const int b   = blk >> 7;              // 8 batches x 128 s-groups
    const int s0  = (blk & 127) * EPI_TOK;
    const float* zb = z + (size_t)b * CDIM * SPAT + s0;

    // ---- stage X tile fp32 (coalesced over s; 32 s x 4B = full lines) ----
    {
        const int s  = tid & 31;
        const int c0 = tid >> 5;   // 0..7
#pragma unroll 4
        for (int c = c0; c < CDIM; c += 8)
            Xs[s * XSTR + c] = zb[(size_t)c * SPAT + s];
    }
    __syncthreads();

    // ---- exact re-rank: 8 threads/token, all-cand partials per 32-ch slice ----
    {
        const int t = tid >> 3, h = tid & 7;
        const unsigned short* cp =
            (const unsigned short*)((int*)ws + WS_CAND) + ((size_t)blk * EPI_TOK + t) * 8;
        const int mycand = cp[h];
        const float en_h = ws[WS_ENORM + mycand];   // hoisted: hides under dots

        int cand[8];
        {
            const ushort4 ca = *(const ushort4*)cp;
            const ushort4 cb = *(const ushort4*)(cp + 4);
            cand[0] = ca.x; cand[1] = ca.y; cand[2] = ca.z; cand[3] = ca.w;
            cand[4] = cb.x; cand[5] = cb.y; cand[6] = cb.z; cand[7] = cb.w;
        }

        // x channel slice: 8 float4 at c = h*4 + q*32 (bank-spread by h*4)
        float4 xq[8];
#pragma unroll
        for (int q = 0; q < 8; ++q)
            xq[q] = *(const float4*)&Xs[t * XSTR + q * 32 + h * 4];

        float xn = 0.0f;   // ||x||^2 partial (for loss)
#pragma unroll
        for (int q = 0; q < 8; ++q)
            xn += xq[q].x * xq[q].x + xq[q].y * xq[q].y
                + xq[q].z * xq[q].z + xq[q].w * xq[q].w;
        xn += __shfl_xor(xn, 1, 8);
        xn += __shfl_xor(xn, 2, 8);
        xn += __shfl_xor(xn, 4, 8);   // xn now = full ||x||^2 on all 8 lanes

        float p8[8];
#pragma unroll
        for (int k = 0; k < 8; ++k) {
            const float* er = emb + (size_t)cand[k] * CDIM + h * 4;
            float dp = 0.0f;
#pragma unroll
            for (int q = 0; q < 8; ++q) {
                const float4 e4 = *(const float4*)(er + q * 32);
                dp += xq[q].x * e4.x + xq[q].y * e4.y + xq[q].z * e4.z + xq[q].w * e4.w;
            }
            p8[k] = dp;
        }

        // paired butterfly: lane h ends with full dot of cand h (width 8)
        float np4[4];
#pragma unroll
        for (int k2 = 0; k2 < 4; ++k2) {
            const float own = (h & 1) ? p8[2 * k2 + 1] : p8[2 * k2];
            const float snd = (h & 1) ? p8[2 * k2]     : p8[2 * k2 + 1];
            np4[k2] = own + __shfl_xor(snd, 1, 8);
        }
        float nq2[2];
#pragma unroll
        for (int k3 = 0; k3 < 2; ++k3) {
            const float own = ((h >> 1) & 1) ? np4[2 * k3 + 1] : np4[2 * k3];
            const float snd = ((h >> 1) & 1) ? np4[2 * k3]     : np4[2 * k3 + 1];
            nq2[k3] = own + __shfl_xor(snd, 2, 8);
        }
        const float own = ((h >> 2) & 1) ? nq2[1] : nq2[0];
        const float snd = ((h >> 2) & 1) ? nq2[0] : nq2[1];
        const float dot = own + __shfl_xor(snd, 4, 8);

        // exact fp32 compare, code tie-break (matches reference argmin)
        float bd = en_h - 2.0f * dot;
        int   bi = mycand;
#pragma unroll
        for (int off = 4; off; off >>= 1) {
            const float od = __shfl_xor(bd, off, 8);
            const int   oi = __shfl_xor(bi, off, 8);
            if (od < bd || (od == bd && oi < bi)) { bd = od; bi = oi; }
        }
        if (h == 0) {
            idxs[t]  = bi;
            lloss[t] = xn + bd;                      // sum((x-e)^2) = ||x||^2 + d_win
            out[O_ENC + blk * EPI_TOK + t] = (float)bi;
            ((int*)ws)[WS_IDX + blk * EPI_TOK + t] = bi;
            atomicAdd(ws + WS_COUNTS + bi, 1.0f);
        }
    }
    __syncthreads();

    // ---- e-fill: overwrite Xs with winner rows (coalesced 128B/token-chunk) ----
    {
        const int t = tid >> 3, h = tid & 7;
        const float* ewin = emb + (size_t)idxs[t] * CDIM + h * 4;
#pragma unroll
        for (int q = 0; q < 8; ++q)
            *(float4*)&Xs[t * XSTR + q * 32 + h * 4] = *(const float4*)(ewin + q * 32);
    }
    __syncthreads();

    // ---- pure quant column write (coalesced over s; full 128B lines) ----
    {
        const int s  = tid & 31;
        const int c0 = tid >> 5;
        float* qcol = out + O_QUANT + (size_t)b * CDIM * SPAT + s0 + s;
#pragma unroll 4
        for (int c = c0; c < CDIM; c += 8)
            qcol[(size_t)c * SPAT] = Xs[s * XSTR + c];
    }
    if (tid == 0) {
        float ls = 0.0f;
#pragma unroll
        for (int t = 0; t < EPI_TOK; ++t) ls += lloss[t];
        atomicAdd(ws + WS_LOSS, ls);
    }
}

// ---- finalize: new_N / perplexity / loss  +  exclusive scan of counts ----
__global__ void k_finalize(const float* __restrict__ Nin, float* __restrict__ ws,
                           float* __restrict__ out) {
    __shared__ float r1[4], r2[4];
    __shared__ int   wsum[4];
    const int tid  = threadIdx.x;
    const int base = tid * 8;                       // contiguous 8 codes/thread

    float cnt[8];
    {
        const float4 c0 = *(const float4*)(ws + WS_COUNTS + base);
        const float4 c1 = *(const float4*)(ws + WS_COUNTS + base + 4);
        cnt[0] = c0.x; cnt[1] = c0.y; cnt[2] = c0.z; cnt[3] = c0.w;
        cnt[4] = c1.x; cnt[5] = c1.y; cnt[6] = c1.z; cnt[7] = c1.w;
    }

    float nsum = 0.0f, H = 0.0f;
    int   tsum = 0;
#pragma unroll
    for (int j = 0; j < 8; ++j) {
        const float cf = cnt[j];
        const float nn = Nin[base + j] * 0.99f + 0.01f * cf;
        out[O_NN + base + j] = nn;
        nsum += nn;
        const float p = cf * (1.0f / 32768.0f);
        H += p * logf(p + 1e-10f);
        tsum += (int)cf;
    }

    // wave-inclusive scan of tsum
    int inc = tsum;
#pragma unroll
    for (int off = 1; off < 64; off <<= 1) {
        const int v = __shfl_up(inc, off, 64);
        if ((tid & 63) >= off) inc += v;
    }
    const int wv = tid >> 6, ln = tid & 63;
    if (ln == 63) wsum[wv] = inc;

#pragma unroll
    for (int off = 32; off; off >>= 1) {
        nsum += __shfl_down(nsum, off);
        H    += __shfl_down(H, off);
    }
    if (ln == 0) { r1[wv] = nsum; r2[wv] = H; }
    __syncthreads();

    int wbase = 0;
    for (int q = 0; q < wv; ++q) wbase += wsum[q];
    int run = wbase + inc - tsum;                    // exclusive prefix for base
    int* offp = (int*)ws + WS_OFF;
    int* curp = (int*)ws + WS_CUR;
#pragma unroll
    for (int j = 0; j < 8; ++j) {
        offp[base + j] = run;
        curp[base + j] = run;
        run += (int)cnt[j];
    }

    if (tid == 0) {
        const float nt = r1[0] + r1[1] + r1[2] + r1[3];
        const float Ht = r2[0] + r2[1] + r2[2] + r2[3];
        ws[WS_N] = nt;
        out[O_PERP] = expf(-Ht);
        out[O_LOSS] = 0.25f * ws[WS_LOSS] * (1.0f / 8388608.0f);
    }
}

// ---- counting-sort scatter: token ids + codes grouped by code ----
__global__ void k_scatter(float* __restrict__ ws) {
    const int t    = blockIdx.x * 256 + threadIdx.x;
    const int code = ((const int*)ws)[WS_IDX + t];
    const int slot = atomicAdd((int*)ws + WS_CUR + code, 1);
    ((int*)ws)[WS_SORT  + slot] = t;
    ((int*)ws)[WS_SCODE + slot] = code;
}

// ---- segmented reduction over sorted tokens: run-aggregated ESUM atomics ----
__global__ __launch_bounds__(256) void k_gather(float* __restrict__ ws) {
    __shared__ int stok[64], scod[64];
    const int g = blockIdx.x, tid = threadIdx.x, c = tid;
    if (tid < 64) {
        stok[tid] = ((const int*)ws)[WS_SORT  + g * 64 + tid];
        scod[tid] = ((const int*)ws)[WS_SCODE + g * 64 + tid];
    }
    __syncthreads();

    const _Float16* xh = (const _Float16*)(ws + WS_XH);
    float* esum = ws + WS_ESUM;

    float acc = 0.0f;
    for (int k0 = 0; k0 < 64; k0 += 8) {
        float v[8];
#pragma unroll
        for (int j = 0; j < 8; ++j)
            v[j] = (float)xh[(size_t)stok[k0 + j] * CDIM + c];
#pragma unroll
        for (int j = 0; j < 8; ++j) {
            const int k = k0 + j;
            acc += v[j];
            if (k == 63 || scod[k] != scod[k + 1]) {
                atomicAdd(&esum[(size_t)scod[k] * CDIM + c], acc);
                acc = 0.0f;
            }
        }
    }
}

// ---- EMA update from ESUM (coalesced, trivial) ----
__global__ __launch_bounds__(256) void k_update(
    const float* __restrict__ zavg, const float* __restrict__ krand,
    const float* __restrict__ ws, float* __restrict__ out)
{
    const int i = blockIdx.x, c = threadIdx.x;
    const float nn  = out[O_NN + i];
    const float n   = ws[WS_N];
    const float wgt = (nn + 1e-7f) / (n + NCODES * 1e-7f) * n;
    const size_t o  = (size_t)i * CDIM + c;
    const float ez  = 0.99f * zavg[o] + 0.01f * ws[WS_ESUM + o];
    out[O_ZAVG + o] = ez;
    out[O_EMB + o]  = (nn >= 1.0f) ? (ez / wgt) : krand[o];
}

extern "C" void kernel_launch(void* const* d_in, const int* in_sizes, int n_in,
                              void* d_out, int out_size, void* d_ws, size_t ws_size,
                              hipStream_t stream) {
    const float* z     = (const float*)d_in[0];
    const float* emb   = (const float*)d_in[1];
    const float* Nin   = (const float*)d_in[2];
    const float* zavg  = (const float*)d_in[3];
    const float* krand = (const float*)d_in[4];
    float* out = (float*)d_out;
    float* ws  = (float*)d_ws;

    // zero counts + loss + N + ESUM each call (one contiguous region)
    hipMemsetAsync(ws + WS_COUNTS, 0,
                   (size_t)(2048 + 4 + NCODES * CDIM) * sizeof(float), stream);

    k_ecvt    <<<NCODES / 8,  256, 0, stream>>>(emb, ws);
    k_main    <<<512,         256, 0, stream>>>(z, ws);
    k_epi     <<<1024,        256, 0, stream>>>(z, emb, ws, out);
    k_finalize<<<1,           256, 0, stream>>>(Nin, ws, out);
    k_scatter <<<NTOK / 256,  256, 0, stream>>>(ws);
    k_gather  <<<NTOK / 64,   256, 0, stream>>>(ws);
    k_update  <<<NCODES,      256, 0, stream>>>(zavg, krand, ws, out);
}

// Round 9
// 138.245 us; speedup vs baseline: 1.0141x; 1.0141x over previous
//
#include <hip/hip_runtime.h>
#include <math.h>

// Problem constants
#define NCODES 2048
#define CDIM   256
#define SPAT   4096            // T*H*W
#define NTOK   32768
#define XSTR   260             // fp32 Xs row stride in k_epi (1040B, 16B-aligned)
#define EPI_TOK 32             // tokens per k_epi block (33.3KB Xs -> 4 blocks/CU, full-line IO)

// k_main geometry: 512 blocks = 256 token-groups(128 tok) x 2 code-halves
#define ETILE    32            // codes per staged tile
#define HALFCODE 1024
#define NTILES   (HALFCODE / ETILE)   // 32

typedef _Float16 half8  __attribute__((ext_vector_type(8)));
typedef float    f32x4  __attribute__((ext_vector_type(4)));

// ws layout (float offsets)
#define WS_ENORM  0         // 2048
#define WS_COUNTS 2048      // 2048
#define WS_LOSS   4096
#define WS_N      4097
#define WS_ESUM   4100      // 2048*256 floats (memset with counts: [2048, 528388))
#define WS_IDX    528388    // int[32768] token -> code
#define WS_OFF    561156    // int[2048] exclusive-scan offsets
#define WS_CUR    563204    // int[2048] scatter cursors
#define WS_SORT   565252    // int[32768] token ids sorted by code
#define WS_SCODE  598020    // int[32768] code per sorted slot
#define WS_CAND   630788    // 16B-aligned; 32768 tok x 8 ushort
#define WS_E16    761860    // 16B-aligned; fp16 swizzled codebook image (1 MB)
#define WS_XH     1024004   // 16B-aligned; fp16 token-major z image (16.8 MB)

// d_out layout (float offsets)
#define O_QUANT 0
#define O_ENC   8388608
#define O_LOSS  8421376
#define O_PERP  8421377
#define O_EMB   8421378
#define O_NN    8945666
#define O_ZAVG  8947714

__device__ inline void gl_lds16(const void* g, void* l) {
    __builtin_amdgcn_global_load_lds(
        (const __attribute__((address_space(1))) void*)g,
        (__attribute__((address_space(3))) void*)l, 16, 0, 0);
}

__device__ inline unsigned umn(unsigned a, unsigned b) { return a < b ? a : b; }
__device__ inline unsigned umx(unsigned a, unsigned b) { return a > b ? a : b; }
__device__ inline unsigned shflx16(unsigned v, int off) {
    return (unsigned)__shfl_xor((int)v, off, 16);
}

// ---- codebook prep: fp16 swizzled LDS-image + row norms (once per call) ----
__global__ void k_ecvt(const float* __restrict__ emb, float* __restrict__ ws) {
    const int tid  = threadIdx.x;
    const int code = (blockIdx.x << 3) + (tid >> 5);   // 8 codes/block
    const int cg   = tid & 31;                         // c = cg*8
    const float* src = emb + (size_t)code * CDIM + (cg << 3);
    const float4 f0 = *(const float4*)src;
    const float4 f1 = *(const float4*)(src + 4);
    half8 h = { (_Float16)f0.x, (_Float16)f0.y, (_Float16)f0.z, (_Float16)f0.w,
                (_Float16)f1.x, (_Float16)f1.y, (_Float16)f1.z, (_Float16)f1.w };
    char* dst = (char*)(ws + WS_E16) + (size_t)code * 512 + ((cg ^ (code & 7)) << 4);
    *(half8*)dst = h;
    float s = f0.x * f0.x + f0.y * f0.y + f0.z * f0.z + f0.w * f0.w
            + f1.x * f1.x + f1.y * f1.y + f1.z * f1.z + f1.w * f1.w;
#pragma unroll
    for (int off = 16; off; off >>= 1) s += __shfl_down(s, off, 32);
    if (cg == 0) ws[WS_ENORM + code] = s;   // exact norm (k_epi re-rank uses it)
}

// ---------------- MFMA distance + top-4-per-half candidate kernel ----------------
// 512 blocks x 256 threads (4 waves). Block = (128 tokens) x (code-half of 1024).
// XCD pair-swizzle: both half-blocks of a token group land on one XCD, so the
// group's 131KB z-slice is HBM-read once and L2-served for the second half.
// Wave = 32 tokens (2 A-sets of 16): each B ds_read feeds 2 MFMAs.
// e-norms are staged into LDS (Ens) in the prologue: the tile loop's ONLY
// vmem is the E-stage DMA, so the fold no longer forces a mid-tile vmcnt(0)
// drain of the prefetch flight (round-7 loaded e-norms from global per tile,
// which drained vmcnt at the fold every tile).
// ch==0 blocks also dump their fp16 A-frags as the token-major Xh image.
__global__ __launch_bounds__(256, 3) void k_main(
    const float* __restrict__ z, float* __restrict__ ws)
{
    __shared__ half8 Es8[2][ETILE][32];   // 32 KB total
    __shared__ float Ens[HALFCODE];       // 4 KB e-norms for this half

    const int tid = threadIdx.x;
    const int raw = blockIdx.x;
    const int xcd = raw & 7, sub = raw >> 3;   // 512 = 8 XCDs x 64 subs
    const int tb  = xcd * 32 + (sub >> 1);     // token group 0..255
    const int ch  = sub & 1;                   // code half
    const int b   = tb >> 5;
    const int s0  = (tb & 31) * 128;
    const float* zb = z + (size_t)b * CDIM * SPAT + s0;
    const char* e16g = (const char*)(ws + WS_E16) + (size_t)ch * HALFCODE * 512;

    const int l  = tid & 63, w = tid >> 6;
    const int lr = l & 15, lg = l >> 4;

    // ---- stage E(0): 16KB, 4 DMA per thread, wave-uniform LDS base ----
    {
        char* dst = (char*)&Es8[0][0][0];
#pragma unroll
        for (int q = 0; q < 4; ++q) {
            const int off = ((q << 2) + w) << 10;
            gl_lds16(e16g + off + (l << 4), dst + off);
        }
    }
    // ---- stage e-norms (4KB): one 16B DMA per thread, lane-linear dest ----
    gl_lds16((const char*)(ws + WS_ENORM + ch * HALFCODE) + (tid << 4),
             (char*)Ens + (tid << 4));

    // ---- A-frags: 2 sets x 8 ks, global -> registers (overlaps E(0) DMA) ----
    half8 a[2][8];
#pragma unroll
    for (int as = 0; as < 2; ++as)
#pragma unroll
    for (int ks = 0; ks < 8; ++ks) {
        float v[8];
#pragma unroll
        for (int e = 0; e < 8; ++e)
            v[e] = zb[(size_t)(ks * 32 + lg * 8 + e) * SPAT + (w * 32 + as * 16 + lr)];
        half8 h = { (_Float16)v[0], (_Float16)v[1], (_Float16)v[2], (_Float16)v[3],
                    (_Float16)v[4], (_Float16)v[5], (_Float16)v[6], (_Float16)v[7] };
        a[as][ks] = h;
    }

    // ---- Xh dump (ch==0 blocks only): token-major fp16 rows from A-frags ----
    if (ch == 0) {
        _Float16* xh = (_Float16*)(ws + WS_XH);
#pragma unroll
        for (int as = 0; as < 2; ++as) {
            _Float16* xr = xh + (size_t)(b * SPAT + s0 + w * 32 + as * 16 + lr) * CDIM;
#pragma unroll
            for (int ks = 0; ks < 8; ++ks)
                *(half8*)(xr + ks * 32 + lg * 8) = a[as][ks];
        }
    }

    unsigned kb0[2][4], kb1[2][4];   // top-2 packed keys per (A-set, r) slot
#pragma unroll
    for (int as = 0; as < 2; ++as)
#pragma unroll
    for (int r = 0; r < 4; ++r) { kb0[as][r] = 0xFFFFFFFFu; kb1[as][r] = 0xFFFFFFFFu; }

    __syncthreads();   // E(0) + Ens landed (barrier drains vmcnt)

    int p = 0;
    for (int tile = 0; tile < NTILES; ++tile) {
        // ---- issue E(tile+1) DMA first: flight covered by MFMA+fold below ----
        if (tile < NTILES - 1) {
            const char* src = e16g + (size_t)(tile + 1) * (ETILE * 512);
            char* dst = (char*)&Es8[p ^ 1][0][0];
#pragma unroll
            for (int q = 0; q < 4; ++q) {
                const int off = ((q << 2) + w) << 10;
                gl_lds16(src + off + (l << 4), dst + off);
            }
        }

        // e-norms from LDS: no vmem dependency in the loop body
        const float en0 = Ens[tile * ETILE + lr];
        const float en1 = Ens[tile * ETILE + 16 + lr];

        f32x4 acc[2][2];
#pragma unroll
        for (int as = 0; as < 2; ++as)
#pragma unroll
        for (int j = 0; j < 2; ++j) acc[as][j] = (f32x4)0.0f;

        // ---- ks-loop, register double-buffered B frags; each B read -> 2 MFMAs
        half8 bf0[2], bf1[2];
#pragma unroll
        for (int j = 0; j < 2; ++j) {
            const int row = j * 16 + lr;
            bf0[j] = Es8[p][row][lg ^ (row & 7)];
        }
#pragma unroll
        for (int ks = 0; ks < 8; ++ks) {
            if (ks < 7) {
#pragma unroll
                for (int j = 0; j < 2; ++j) {
                    const int row = j * 16 + lr;
                    if (ks & 1) bf0[j] = Es8[p][row][((ks + 1) * 4 + lg) ^ (row & 7)];
                    else        bf1[j] = Es8[p][row][((ks + 1) * 4 + lg) ^ (row & 7)];
                }
            }
            __builtin_amdgcn_s_setprio(1);
#pragma unroll
            for (int as = 0; as < 2; ++as)
#pragma unroll
            for (int j = 0; j < 2; ++j)
                acc[as][j] = __builtin_amdgcn_mfma_f32_16x16x32_f16(
                    a[as][ks], (ks & 1) ? bf1[j] : bf0[j], acc[as][j], 0, 0, 0);
            __builtin_amdgcn_s_setprio(0);
        }

        // ---- fold into per-lane top-2 packed keys (5 VALU per value) ----
        const float enb0 = en0 + 4096.0f;
        const float enb1 = en1 + 4096.0f;
        const unsigned code0 = (unsigned)(ch * HALFCODE + tile * ETILE + lr);
        const unsigned code1 = code0 + 16u;
#pragma unroll
        for (int as = 0; as < 2; ++as)
#pragma unroll
        for (int r = 0; r < 4; ++r) {
            {
                const float d = fmaf(acc[as][0][r], -2.0f, enb0);
                const unsigned key = (__float_as_uint(d) & 0xFFFFF800u) | code0;
                const unsigned hi = umx(kb0[as][r], key);
                kb0[as][r] = umn(kb0[as][r], key);
                kb1[as][r] = umn(kb1[as][r], hi);
            }
            {
                const float d = fmaf(acc[as][1][r], -2.0f, enb1);
                const unsigned key = (__float_as_uint(d) & 0xFFFFF800u) | code1;
                const unsigned hi = umx(kb0[as][r], key);
                kb0[as][r] = umn(kb0[as][r], key);
                kb1[as][r] = umn(kb1[as][r], hi);
            }
        }

        __syncthreads();   // E(tile+1) landed; all reads of buf p done
        p ^= 1;
    }

    // ---- 16-lane bitonic merge of sorted-4 key lists -> top-4 per token ----
#pragma unroll
    for (int as = 0; as < 2; ++as)
#pragma unroll
    for (int r = 0; r < 4; ++r) {
        unsigned k0 = kb0[as][r], k1 = kb1[as][r];
        unsigned k2 = 0xFFFFFFFFu, k3 = 0xFFFFFFFFu;
#pragma unroll
        for (int off = 8; off; off >>= 1) {
            const unsigned o0 = shflx16(k0, off);
            const unsigned o1 = shflx16(k1, off);
            const unsigned o2 = shflx16(k2, off);
            const unsigned o3 = shflx16(k3, off);
            // lowest-4 of two ascending 4-lists: min with reversed other -> bitonic
            const unsigned m0 = umn(k0, o3), m1 = umn(k1, o2);
            const unsigned m2 = umn(k2, o1), m3 = umn(k3, o0);
            // sort the bitonic 4-sequence
            const unsigned t0 = umn(m0, m2), t2 = umx(m0, m2);
            const unsigned t1 = umn(m1, m3), t3 = umx(m1, m3);
            k0 = umn(t0, t1); k1 = umx(t0, t1);
            k2 = umn(t2, t3); k3 = umx(t2, t3);
        }
        if (lr == 0) {
            const int tokg = b * SPAT + s0 + w * 32 + as * 16 + lg * 4 + r;
            ushort4 c4;
            c4.x = (unsigned short)(k0 & 2047u);
            c4.y = (unsigned short)(k1 & 2047u);
            c4.z = (unsigned short)(k2 & 2047u);
            c4.w = (unsigned short)(k3 & 2047u);
            *(ushort4*)((unsigned short*)((int*)ws + WS_CAND) + (size_t)tokg * 8 + ch * 4) = c4;
        }
    }
}

// ---------------- exact fp32 re-rank (8 cands) + epilogue ----------------
// 1024 blocks x 256 threads, 32 tokens/block, Xs 33.3KB -> 4 blocks/CU.
// EPI_TOK=32 => 128B full-line z reads and quant writes.
__global__ __launch_bounds__(256, 4) void k_epi(
    const float* __restrict__ z, const float* __restrict__ emb,
    float* __restrict__ ws, float* __restrict__ out)
{
    __shared__ float Xs[EPI_TOK * XSTR];   // 33280 B fp32
    __shared__ int   idxs[EPI_TOK];
    __shared__ float lloss[EPI_TOK];

    const int tid = threadIdx.x, blk = blockIdx.x;
    const int b   = blk >> 7;              // 8 batches x 128 s-groups
    const int s0  = (blk & 127) * EPI_TOK;
    const float* zb = z + (size_t)b * CDIM * SPAT + s0;

    // ---- stage X tile fp32 (coalesced over s; 32 s x 4B = full lines) ----
    {
        const int s  = tid & 31;
        const int c0 = tid >> 5;   // 0..7
#pragma unroll 4
        for (int c = c0; c < CDIM; c += 8)
            Xs[s * XSTR + c] = zb[(size_t)c * SPAT + s];
    }
    __syncthreads();

    // ---- exact re-rank: 8 threads/token, all-cand partials per 32-ch slice ----
    {
        const int t = tid >> 3, h = tid & 7;
        const unsigned short* cp =
            (const unsigned short*)((int*)ws + WS_CAND) + ((size_t)blk * EPI_TOK + t) * 8;
        const int mycand = cp[h];
        const float en_h = ws[WS_ENORM + mycand];   // hoisted: hides under dots

        int cand[8];
        {
            const ushort4 ca = *(const ushort4*)cp;
            const ushort4 cb = *(const ushort4*)(cp + 4);
            cand[0] = ca.x; cand[1] = ca.y; cand[2] = ca.z; cand[3] = ca.w;
            cand[4] = cb.x; cand[5] = cb.y; cand[6] = cb.z; cand[7] = cb.w;
        }

        // x channel slice: 8 float4 at c = h*4 + q*32 (bank-spread by h*4)
        float4 xq[8];
#pragma unroll
        for (int q = 0; q < 8; ++q)
            xq[q] = *(const float4*)&Xs[t * XSTR + q * 32 + h * 4];

        float xn = 0.0f;   // ||x||^2 partial (for loss)
#pragma unroll
        for (int q = 0; q < 8; ++q)
            xn += xq[q].x * xq[q].x + xq[q].y * xq[q].y
                + xq[q].z * xq[q].z + xq[q].w * xq[q].w;
        xn += __shfl_xor(xn, 1, 8);
        xn += __shfl_xor(xn, 2, 8);
        xn += __shfl_xor(xn, 4, 8);   // xn now = full ||x||^2 on all 8 lanes

        float p8[8];
#pragma unroll
        for (int k = 0; k < 8; ++k) {
            const float* er = emb + (size_t)cand[k] * CDIM + h * 4;
            float dp = 0.0f;
#pragma unroll
            for (int q = 0; q < 8; ++q) {
                const float4 e4 = *(const float4*)(er + q * 32);
                dp += xq[q].x * e4.x + xq[q].y * e4.y + xq[q].z * e4.z + xq[q].w * e4.w;
            }
            p8[k] = dp;
        }

        // paired butterfly: lane h ends with full dot of cand h (width 8)
        float np4[4];
#pragma unroll
        for (int k2 = 0; k2 < 4; ++k2) {
            const float own = (h & 1) ? p8[2 * k2 + 1] : p8[2 * k2];
            const float snd = (h & 1) ? p8[2 * k2]     : p8[2 * k2 + 1];
            np4[k2] = own + __shfl_xor(snd, 1, 8);
        }
        float nq2[2];
#pragma unroll
        for (int k3 = 0; k3 < 2; ++k3) {
            const float own = ((h >> 1) & 1) ? np4[2 * k3 + 1] : np4[2 * k3];
            const float snd = ((h >> 1) & 1) ? np4[2 * k3]     : np4[2 * k3 + 1];
            nq2[k3] = own + __shfl_xor(snd, 2, 8);
        }
        const float own = ((h >> 2) & 1) ? nq2[1] : nq2[0];
        const float snd = ((h >> 2) & 1) ? nq2[0] : nq2[1];
        const float dot = own + __shfl_xor(snd, 4, 8);

        // exact fp32 compare, code tie-break (matches reference argmin)
        float bd = en_h - 2.0f * dot;
        int   bi = mycand;
#pragma unroll
        for (int off = 4; off; off >>= 1) {
            const float od = __shfl_xor(bd, off, 8);
            const int   oi = __shfl_xor(bi, off, 8);
            if (od < bd || (od == bd && oi < bi)) { bd = od; bi = oi; }
        }
        if (h == 0) {
            idxs[t]  = bi;
            lloss[t] = xn + bd;                      // sum((x-e)^2) = ||x||^2 + d_win
            out[O_ENC + blk * EPI_TOK + t] = (float)bi;
            ((int*)ws)[WS_IDX + blk * EPI_TOK + t] = bi;
            atomicAdd(ws + WS_COUNTS + bi, 1.0f);
        }
    }
    __syncthreads();

    // ---- e-fill: overwrite Xs with winner rows (coalesced 128B/token-chunk) ----
    {
        const int t = tid >> 3, h = tid & 7;
        const float* ewin = emb + (size_t)idxs[t] * CDIM + h * 4;
#pragma unroll
        for (int q = 0; q < 8; ++q)
            *(float4*)&Xs[t * XSTR + q * 32 + h * 4] = *(const float4*)(ewin + q * 32);
    }
    __syncthreads();

    // ---- pure quant column write (coalesced over s; full 128B lines) ----
    {
        const int s  = tid & 31;
        const int c0 = tid >> 5;
        float* qcol = out + O_QUANT + (size_t)b * CDIM * SPAT + s0 + s;
#pragma unroll 4
        for (int c = c0; c < CDIM; c += 8)
            qcol[(size_t)c * SPAT] = Xs[s * XSTR + c];
    }
    if (tid == 0) {
        float ls = 0.0f;
#pragma unroll
        for (int t = 0; t < EPI_TOK; ++t) ls += lloss[t];
        atomicAdd(ws + WS_LOSS, ls);
    }
}

// ---- finalize: new_N / perplexity / loss  +  exclusive scan of counts ----
__global__ void k_finalize(const float* __restrict__ Nin, float* __restrict__ ws,
                           float* __restrict__ out) {
    __shared__ float r1[4], r2[4];
    __shared__ int   wsum[4];
    const int tid  = threadIdx.x;
    const int base = tid * 8;                       // contiguous 8 codes/thread

    float cnt[8];
    {
        const float4 c0 = *(const float4*)(ws + WS_COUNTS + base);
        const float4 c1 = *(const float4*)(ws + WS_COUNTS + base + 4);
        cnt[0] = c0.x; cnt[1] = c0.y; cnt[2] = c0.z; cnt[3] = c0.w;
        cnt[4] = c1.x; cnt[5] = c1.y; cnt[6] = c1.z; cnt[7] = c1.w;
    }

    float nsum = 0.0f, H = 0.0f;
    int   tsum = 0;
#pragma unroll
    for (int j = 0; j < 8; ++j) {
        const float cf = cnt[j];
        const float nn = Nin[base + j] * 0.99f + 0.01f * cf;
        out[O_NN + base + j] = nn;
        nsum += nn;
        const float p = cf * (1.0f / 32768.0f);
        H += p * logf(p + 1e-10f);
        tsum += (int)cf;
    }

    // wave-inclusive scan of tsum
    int inc = tsum;
#pragma unroll
    for (int off = 1; off < 64; off <<= 1) {
        const int v = __shfl_up(inc, off, 64);
        if ((tid & 63) >= off) inc += v;
    }
    const int wv = tid >> 6, ln = tid & 63;
    if (ln == 63) wsum[wv] = inc;

#pragma unroll
    for (int off = 32; off; off >>= 1) {
        nsum += __shfl_down(nsum, off);
        H    += __shfl_down(H, off);
    }
    if (ln == 0) { r1[wv] = nsum; r2[wv] = H; }
    __syncthreads();

    int wbase = 0;
    for (int q = 0; q < wv; ++q) wbase += wsum[q];
    int run = wbase + inc - tsum;                    // exclusive prefix for base
    int* offp = (int*)ws + WS_OFF;
    int* curp = (int*)ws + WS_CUR;
#pragma unroll
    for (int j = 0; j < 8; ++j) {
        offp[base + j] = run;
        curp[base + j] = run;
        run += (int)cnt[j];
    }

    if (tid == 0) {
        const float nt = r1[0] + r1[1] + r1[2] + r1[3];
        const float Ht = r2[0] + r2[1] + r2[2] + r2[3];
        ws[WS_N] = nt;
        out[O_PERP] = expf(-Ht);
        out[O_LOSS] = 0.25f * ws[WS_LOSS] * (1.0f / 8388608.0f);
    }
}

// ---- counting-sort scatter: token ids + codes grouped by code ----
__global__ void k_scatter(float* __restrict__ ws) {
    const int t    = blockIdx.x * 256 + threadIdx.x;
    const int code = ((const int*)ws)[WS_IDX + t];
    const int slot = atomicAdd((int*)ws + WS_CUR + code, 1);
    ((int*)ws)[WS_SORT  + slot] = t;
    ((int*)ws)[WS_SCODE + slot] = code;
}

// ---- segmented reduction over sorted tokens: run-aggregated ESUM atomics ----
__global__ __launch_bounds__(256) void k_gather(float* __restrict__ ws) {
    __shared__ int stok[64], scod[64];
    const int g = blockIdx.x, tid = threadIdx.x, c = tid;
    if (tid < 64) {
        stok[tid] = ((const int*)ws)[WS_SORT  + g * 64 + tid];
        scod[tid] = ((const int*)ws)[WS_SCODE + g * 64 + tid];
    }
    __syncthreads();

    const _Float16* xh = (const _Float16*)(ws + WS_XH);
    float* esum = ws + WS_ESUM;

    float acc = 0.0f;
    for (int k0 = 0; k0 < 64; k0 += 8) {
        float v[8];
#pragma unroll
        for (int j = 0; j < 8; ++j)
            v[j] = (float)xh[(size_t)stok[k0 + j] * CDIM + c];
#pragma unroll
        for (int j = 0; j < 8; ++j) {
            const int k = k0 + j;
            acc += v[j];
            if (k == 63 || scod[k] != scod[k + 1]) {
                atomicAdd(&esum[(size_t)scod[k] * CDIM + c], acc);
                acc = 0.0f;
            }
        }
    }
}

// ---- EMA update from ESUM (coalesced, trivial) ----
__global__ __launch_bounds__(256) void k_update(
    const float* __restrict__ zavg, const float* __restrict__ krand,
    const float* __restrict__ ws, float* __restrict__ out)
{
    const int i = blockIdx.x, c = threadIdx.x;
    const float nn  = out[O_NN + i];
    const float n   = ws[WS_N];
    const float wgt = (nn + 1e-7f) / (n + NCODES * 1e-7f) * n;
    const size_t o  = (size_t)i * CDIM + c;
    const float ez  = 0.99f * zavg[o] + 0.01f * ws[WS_ESUM + o];
    out[O_ZAVG + o] = ez;
    out[O_EMB + o]  = (nn >= 1.0f) ? (ez / wgt) : krand[o];
}

extern "C" void kernel_launch(void* const* d_in, const int* in_sizes, int n_in,
                              void* d_out, int out_size, void* d_ws, size_t ws_size,
                              hipStream_t stream) {
    const float* z     = (const float*)d_in[0];
    const float* emb   = (const float*)d_in[1];
    const float* Nin   = (const float*)d_in[2];
    const float* zavg  = (const float*)d_in[3];
    const float* krand = (const float*)d_in[4];
    float* out = (float*)d_out;
    float* ws  = (float*)d_ws;

    // zero counts + loss + N + ESUM each call (one contiguous region)
    hipMemsetAsync(ws + WS_COUNTS, 0,
                   (size_t)(2048 + 4 + NCODES * CDIM) * sizeof(float), stream);

    k_ecvt    <<<NCODES / 8,  256, 0, stream>>>(emb, ws);
    k_main    <<<512,         256, 0, stream>>>(z, ws);
    k_epi     <<<1024,        256, 0, stream>>>(z, emb, ws, out);
    k_finalize<<<1,           256, 0, stream>>>(Nin, ws, out);
    k_scatter <<<NTOK / 256,  256, 0, stream>>>(ws);
    k_gather  <<<NTOK / 64,   256, 0, stream>>>(ws);
    k_update  <<<NCODES,      256, 0, stream>>>(zavg, krand, ws, out);
}

// Round 10
// 138.140 us; speedup vs baseline: 1.0148x; 1.0008x over previous
//
#include <hip/hip_runtime.h>
#include <math.h>

// Problem constants
#define NCODES 2048
#define CDIM   256
#define SPAT   4096            // T*H*W
#define NTOK   32768
#define XSTR   260             // fp32 Xs row stride in k_epi (1040B, 16B-aligned)
#define EPI_TOK 32             // tokens per k_epi block (33.3KB Xs -> 4 blocks/CU, full-line IO)

// k_main geometry: 1024 blocks = 512 token-groups(64 tok) x 2 code-halves,
// 128 threads (2 waves) per block -> 4 blocks/CU (4 independent barrier domains).
#define ETILE    32            // codes per staged tile
#define HALFCODE 1024
#define NTILES   (HALFCODE / ETILE)   // 32

typedef _Float16 half8  __attribute__((ext_vector_type(8)));
typedef float    f32x4  __attribute__((ext_vector_type(4)));

// ws layout (float offsets)
#define WS_ENORM  0         // 2048
#define WS_COUNTS 2048      // 2048
#define WS_LOSS   4096
#define WS_N      4097
#define WS_ESUM   4100      // 2048*256 floats (memset with counts: [2048, 528388))
#define WS_IDX    528388    // int[32768] token -> code
#define WS_OFF    561156    // int[2048] exclusive-scan offsets
#define WS_CUR    563204    // int[2048] scatter cursors
#define WS_SORT   565252    // int[32768] token ids sorted by code
#define WS_SCODE  598020    // int[32768] code per sorted slot
#define WS_CAND   630788    // 16B-aligned; 32768 tok x 8 ushort
#define WS_E16    761860    // 16B-aligned; fp16 swizzled codebook image (1 MB)
#define WS_XH     1024004   // 16B-aligned; fp16 token-major z image (16.8 MB)

// d_out layout (float offsets)
#define O_QUANT 0
#define O_ENC   8388608
#define O_LOSS  8421376
#define O_PERP  8421377
#define O_EMB   8421378
#define O_NN    8945666
#define O_ZAVG  8947714

__device__ inline void gl_lds16(const void* g, void* l) {
    __builtin_amdgcn_global_load_lds(
        (const __attribute__((address_space(1))) void*)g,
        (__attribute__((address_space(3))) void*)l, 16, 0, 0);
}

__device__ inline unsigned umn(unsigned a, unsigned b) { return a < b ? a : b; }
__device__ inline unsigned umx(unsigned a, unsigned b) { return a > b ? a : b; }
__device__ inline unsigned shflx16(unsigned v, int off) {
    return (unsigned)__shfl_xor((int)v, off, 16);
}

// ---- codebook prep: fp16 swizzled LDS-image + row norms (once per call) ----
__global__ void k_ecvt(const float* __restrict__ emb, float* __restrict__ ws) {
    const int tid  = threadIdx.x;
    const int code = (blockIdx.x << 3) + (tid >> 5);   // 8 codes/block
    const int cg   = tid & 31;                         // c = cg*8
    const float* src = emb + (size_t)code * CDIM + (cg << 3);
    const float4 f0 = *(const float4*)src;
    const float4 f1 = *(const float4*)(src + 4);
    half8 h = { (_Float16)f0.x, (_Float16)f0.y, (_Float16)f0.z, (_Float16)f0.w,
                (_Float16)f1.x, (_Float16)f1.y, (_Float16)f1.z, (_Float16)f1.w };
    char* dst = (char*)(ws + WS_E16) + (size_t)code * 512 + ((cg ^ (code & 7)) << 4);
    *(half8*)dst = h;
    float s = f0.x * f0.x + f0.y * f0.y + f0.z * f0.z + f0.w * f0.w
            + f1.x * f1.x + f1.y * f1.y + f1.z * f1.z + f1.w * f1.w;
#pragma unroll
    for (int off = 16; off; off >>= 1) s += __shfl_down(s, off, 32);
    if (cg == 0) ws[WS_ENORM + code] = s;   // exact norm (k_epi re-rank uses it)
}

// ---------------- MFMA distance + top-4-per-half candidate kernel ----------------
// 1024 blocks x 128 threads (2 waves). Block = (64 tokens) x (code-half of 1024).
// 4 blocks/CU: four independent barrier domains per CU overlap each other's
// stage-drain stalls (the round-7 512x256 config had only 2 -> latency-bound).
// XCD pair-swizzle: both half-blocks of a token group land on one XCD.
// Wave = 32 tokens (2 A-sets of 16): each B ds_read feeds 2 MFMAs (unchanged).
// ch==0 blocks also dump their fp16 A-frags as the token-major Xh image.
__global__ __launch_bounds__(128, 4) void k_main(
    const float* __restrict__ z, float* __restrict__ ws)
{
    __shared__ half8 Es8[2][ETILE][32];   // 32 KB total

    const int tid = threadIdx.x;
    const int raw = blockIdx.x;
    const int xcd = raw & 7, sub = raw >> 3;   // 1024 = 8 XCDs x 128 subs
    const int tb  = xcd * 64 + (sub >> 1);     // token group 0..511
    const int ch  = sub & 1;                   // code half
    const int b   = tb >> 6;
    const int s0  = (tb & 63) * 64;
    const float* zb = z + (size_t)b * CDIM * SPAT + s0;
    const char* e16g = (const char*)(ws + WS_E16) + (size_t)ch * HALFCODE * 512;

    const int l  = tid & 63, w = tid >> 6;     // w in {0,1}
    const int lr = l & 15, lg = l >> 4;

    // ---- stage E(0): 16KB, 8 DMA per thread, wave-uniform LDS base ----
    {
        char* dst = (char*)&Es8[0][0][0];
#pragma unroll
        for (int q = 0; q < 8; ++q) {
            const int off = ((q << 1) + w) << 10;
            gl_lds16(e16g + off + (l << 4), dst + off);
        }
    }

    // ---- A-frags: 2 sets x 8 ks, global -> registers (overlaps E(0) DMA) ----
    half8 a[2][8];
#pragma unroll
    for (int as = 0; as < 2; ++as)
#pragma unroll
    for (int ks = 0; ks < 8; ++ks) {
        float v[8];
#pragma unroll
        for (int e = 0; e < 8; ++e)
            v[e] = zb[(size_t)(ks * 32 + lg * 8 + e) * SPAT + (w * 32 + as * 16 + lr)];
        half8 h = { (_Float16)v[0], (_Float16)v[1], (_Float16)v[2], (_Float16)v[3],
                    (_Float16)v[4], (_Float16)v[5], (_Float16)v[6], (_Float16)v[7] };
        a[as][ks] = h;
    }

    // ---- Xh dump (ch==0 blocks only): token-major fp16 rows from A-frags ----
    if (ch == 0) {
        _Float16* xh = (_Float16*)(ws + WS_XH);
#pragma unroll
        for (int as = 0; as < 2; ++as) {
            _Float16* xr = xh + (size_t)(b * SPAT + s0 + w * 32 + as * 16 + lr) * CDIM;
#pragma unroll
            for (int ks = 0; ks < 8; ++ks)
                *(half8*)(xr + ks * 32 + lg * 8) = a[as][ks];
        }
    }

    unsigned kb0[2][4], kb1[2][4];   // top-2 packed keys per (A-set, r) slot
#pragma unroll
    for (int as = 0; as < 2; ++as)
#pragma unroll
    for (int r = 0; r < 4; ++r) { kb0[as][r] = 0xFFFFFFFFu; kb1[as][r] = 0xFFFFFFFFu; }

    __syncthreads();   // E(0) landed (barrier drains vmcnt)

    int p = 0;
    for (int tile = 0; tile < NTILES; ++tile) {
        // ---- issue E(tile+1) DMA first: flight covered by MFMA+fold below ----
        if (tile < NTILES - 1) {
            const char* src = e16g + (size_t)(tile + 1) * (ETILE * 512);
            char* dst = (char*)&Es8[p ^ 1][0][0];
#pragma unroll
            for (int q = 0; q < 8; ++q) {
                const int off = ((q << 1) + w) << 10;
                gl_lds16(src + off + (l << 4), dst + off);
            }
        }

        // hoist the two e-norm loads so latency hides under the MFMAs
        const float en0 = ws[WS_ENORM + ch * HALFCODE + tile * ETILE + lr];
        const float en1 = ws[WS_ENORM + ch * HALFCODE + tile * ETILE + 16 + lr];

        f32x4 acc[2][2];
#pragma unroll
        for (int as = 0; as < 2; ++as)
#pragma unroll
        for (int j = 0; j < 2; ++j) acc[as][j] = (f32x4)0.0f;

        // ---- ks-loop, register double-buffered B frags; each B read -> 2 MFMAs
        half8 bf0[2], bf1[2];
#pragma unroll
        for (int j = 0; j < 2; ++j) {
            const int row = j * 16 + lr;
            bf0[j] = Es8[p][row][lg ^ (row & 7)];
        }
#pragma unroll
        for (int ks = 0; ks < 8; ++ks) {
            if (ks < 7) {
#pragma unroll
                for (int j = 0; j < 2; ++j) {
                    const int row = j * 16 + lr;
                    if (ks & 1) bf0[j] = Es8[p][row][((ks + 1) * 4 + lg) ^ (row & 7)];
                    else        bf1[j] = Es8[p][row][((ks + 1) * 4 + lg) ^ (row & 7)];
                }
            }
            __builtin_amdgcn_s_setprio(1);
#pragma unroll
            for (int as = 0; as < 2; ++as)
#pragma unroll
            for (int j = 0; j < 2; ++j)
                acc[as][j] = __builtin_amdgcn_mfma_f32_16x16x32_f16(
                    a[as][ks], (ks & 1) ? bf1[j] : bf0[j], acc[as][j], 0, 0, 0);
            __builtin_amdgcn_s_setprio(0);
        }

        // ---- fold into per-lane top-2 packed keys (5 VALU per value) ----
        const float enb0 = en0 + 4096.0f;
        const float enb1 = en1 + 4096.0f;
        const unsigned code0 = (unsigned)(ch * HALFCODE + tile * ETILE + lr);
        const unsigned code1 = code0 + 16u;
#pragma unroll
        for (int as = 0; as < 2; ++as)
#pragma unroll
        for (int r = 0; r < 4; ++r) {
            {
                const float d = fmaf(acc[as][0][r], -2.0f, enb0);
                const unsigned key = (__float_as_uint(d) & 0xFFFFF800u) | code0;
                const unsigned hi = umx(kb0[as][r], key);
                kb0[as][r] = umn(kb0[as][r], key);
                kb1[as][r] = umn(kb1[as][r], hi);
            }
            {
                const float d = fmaf(acc[as][1][r], -2.0f, enb1);
                const unsigned key = (__float_as_uint(d) & 0xFFFFF800u) | code1;
                const unsigned hi = umx(kb0[as][r], key);
                kb0[as][r] = umn(kb0[as][r], key);
                kb1[as][r] = umn(kb1[as][r], hi);
            }
        }

        __syncthreads();   // E(tile+1) landed; all reads of buf p done
        p ^= 1;
    }

    // ---- 16-lane bitonic merge of sorted-4 key lists -> top-4 per token ----
#pragma unroll
    for (int as = 0; as < 2; ++as)
#pragma unroll
    for (int r = 0; r < 4; ++r) {
        unsigned k0 = kb0[as][r], k1 = kb1[as][r];
        unsigned k2 = 0xFFFFFFFFu, k3 = 0xFFFFFFFFu;
#pragma unroll
        for (int off = 8; off; off >>= 1) {
            const unsigned o0 = shflx16(k0, off);
            const unsigned o1 = shflx16(k1, off);
            const unsigned o2 = shflx16(k2, off);
            const unsigned o3 = shflx16(k3, off);
            // lowest-4 of two ascending 4-lists: min with reversed other -> bitonic
            const unsigned m0 = umn(k0, o3), m1 = umn(k1, o2);
            const unsigned m2 = umn(k2, o1), m3 = umn(k3, o0);
            // sort the bitonic 4-sequence
            const unsigned t0 = umn(m0, m2), t2 = umx(m0, m2);
            const unsigned t1 = umn(m1, m3), t3 = umx(m1, m3);
            k0 = umn(t0, t1); k1 = umx(t0, t1);
            k2 = umn(t2, t3); k3 = umx(t2, t3);
        }
        if (lr == 0) {
            const int tokg = b * SPAT + s0 + w * 32 + as * 16 + lg * 4 + r;
            ushort4 c4;
            c4.x = (unsigned short)(k0 & 2047u);
            c4.y = (unsigned short)(k1 & 2047u);
            c4.z = (unsigned short)(k2 & 2047u);
            c4.w = (unsigned short)(k3 & 2047u);
            *(ushort4*)((unsigned short*)((int*)ws + WS_CAND) + (size_t)tokg * 8 + ch * 4) = c4;
        }
    }
}

// ---------------- exact fp32 re-rank (8 cands) + epilogue ----------------
// 1024 blocks x 256 threads, 32 tokens/block, Xs 33.3KB -> 4 blocks/CU.
// EPI_TOK=32 => 128B full-line z reads and quant writes.
__global__ __launch_bounds__(256, 4) void k_epi(
    const float* __restrict__ z, const float* __restrict__ emb,
    float* __restrict__ ws, float* __restrict__ out)
{
    __shared__ float Xs[EPI_TOK * XSTR];   // 33280 B fp32
    __shared__ int   idxs[EPI_TOK];
    __shared__ float lloss[EPI_TOK];

    const int tid = threadIdx.x, blk = blockIdx.x;
    const int b   = blk >> 7;              // 8 batches x 128 s-groups
    const int s0  = (blk & 127) * EPI_TOK;
    const float* zb = z + (size_t)b * CDIM * SPAT + s0;

    // ---- stage X tile fp32 (coalesced over s; 32 s x 4B = full lines) ----
    {
        const int s  = tid & 31;
        const int c0 = tid >> 5;   // 0..7
#pragma unroll 4
        for (int c = c0; c < CDIM; c += 8)
            Xs[s * XSTR + c] = zb[(size_t)c * SPAT + s];
    }
    __syncthreads();

    // ---- exact re-rank: 8 threads/token, all-cand partials per 32-ch slice ----
    {
        const int t = tid >> 3, h = tid & 7;
        const unsigned short* cp =
            (const unsigned short*)((int*)ws + WS_CAND) + ((size_t)blk * EPI_TOK + t) * 8;
        const int mycand = cp[h];
        const float en_h = ws[WS_ENORM + mycand];   // hoisted: hides under dots

        int cand[8];
        {
            const ushort4 ca = *(const ushort4*)cp;
            const ushort4 cb = *(const ushort4*)(cp + 4);
            cand[0] = ca.x; cand[1] = ca.y; cand[2] = ca.z; cand[3] = ca.w;
            cand[4] = cb.x; cand[5] = cb.y; cand[6] = cb.z; cand[7] = cb.w;
        }

        // x channel slice: 8 float4 at c = h*4 + q*32 (bank-spread by h*4)
        float4 xq[8];
#pragma unroll
        for (int q = 0; q < 8; ++q)
            xq[q] = *(const float4*)&Xs[t * XSTR + q * 32 + h * 4];

        float xn = 0.0f;   // ||x||^2 partial (for loss)
#pragma unroll
        for (int q = 0; q < 8; ++q)
            xn += xq[q].x * xq[q].x + xq[q].y * xq[q].y
                + xq[q].z * xq[q].z + xq[q].w * xq[q].w;
        xn += __shfl_xor(xn, 1, 8);
        xn += __shfl_xor(xn, 2, 8);
        xn += __shfl_xor(xn, 4, 8);   // xn now = full ||x||^2 on all 8 lanes

        float p8[8];
#pragma unroll
        for (int k = 0; k < 8; ++k) {
            const float* er = emb + (size_t)cand[k] * CDIM + h * 4;
            float dp = 0.0f;
#pragma unroll
            for (int q = 0; q < 8; ++q) {
                const float4 e4 = *(const float4*)(er + q * 32);
                dp += xq[q].x * e4.x + xq[q].y * e4.y + xq[q].z * e4.z + xq[q].w * e4.w;
            }
            p8[k] = dp;
        }

        // paired butterfly: lane h ends with full dot of cand h (width 8)
        float np4[4];
#pragma unroll
        for (int k2 = 0; k2 < 4; ++k2) {
            const float own = (h & 1) ? p8[2 * k2 + 1] : p8[2 * k2];
            const float snd = (h & 1) ? p8[2 * k2]     : p8[2 * k2 + 1];
            np4[k2] = own + __shfl_xor(snd, 1, 8);
        }
        float nq2[2];
#pragma unroll
        for (int k3 = 0; k3 < 2; ++k3) {
            const float own = ((h >> 1) & 1) ? np4[2 * k3 + 1] : np4[2 * k3];
            const float snd = ((h >> 1) & 1) ? np4[2 * k3]     : np4[2 * k3 + 1];
            nq2[k3] = own + __shfl_xor(snd, 2, 8);
        }
        const float own = ((h >> 2) & 1) ? nq2[1] : nq2[0];
        const float snd = ((h >> 2) & 1) ? nq2[0] : nq2[1];
        const float dot = own + __shfl_xor(snd, 4, 8);

        // exact fp32 compare, code tie-break (matches reference argmin)
        float bd = en_h - 2.0f * dot;
        int   bi = mycand;
#pragma unroll
        for (int off = 4; off; off >>= 1) {
            const float od = __shfl_xor(bd, off, 8);
            const int   oi = __shfl_xor(bi, off, 8);
            if (od < bd || (od == bd && oi < bi)) { bd = od; bi = oi; }
        }
        if (h == 0) {
            idxs[t]  = bi;
            lloss[t] = xn + bd;                      // sum((x-e)^2) = ||x||^2 + d_win
            out[O_ENC + blk * EPI_TOK + t] = (float)bi;
            ((int*)ws)[WS_IDX + blk * EPI_TOK + t] = bi;
            atomicAdd(ws + WS_COUNTS + bi, 1.0f);
        }
    }
    __syncthreads();

    // ---- e-fill: overwrite Xs with winner rows (coalesced 128B/token-chunk) ----
    {
        const int t = tid >> 3, h = tid & 7;
        const float* ewin = emb + (size_t)idxs[t] * CDIM + h * 4;
#pragma unroll
        for (int q = 0; q < 8; ++q)
            *(float4*)&Xs[t * XSTR + q * 32 + h * 4] = *(const float4*)(ewin + q * 32);
    }
    __syncthreads();

    // ---- pure quant column write (coalesced over s; full 128B lines) ----
    {
        const int s  = tid & 31;
        const int c0 = tid >> 5;
        float* qcol = out + O_QUANT + (size_t)b * CDIM * SPAT + s0 + s;
#pragma unroll 4
        for (int c = c0; c < CDIM; c += 8)
            qcol[(size_t)c * SPAT] = Xs[s * XSTR + c];
    }
    if (tid == 0) {
        float ls = 0.0f;
#pragma unroll
        for (int t = 0; t < EPI_TOK; ++t) ls += lloss[t];
        atomicAdd(ws + WS_LOSS, ls);
    }
}

// ---- finalize: new_N / perplexity / loss  +  exclusive scan of counts ----
__global__ void k_finalize(const float* __restrict__ Nin, float* __restrict__ ws,
                           float* __restrict__ out) {
    __shared__ float r1[4], r2[4];
    __shared__ int   wsum[4];
    const int tid  = threadIdx.x;
    const int base = tid * 8;                       // contiguous 8 codes/thread

    float cnt[8];
    {
        const float4 c0 = *(const float4*)(ws + WS_COUNTS + base);
        const float4 c1 = *(const float4*)(ws + WS_COUNTS + base + 4);
        cnt[0] = c0.x; cnt[1] = c0.y; cnt[2] = c0.z; cnt[3] = c0.w;
        cnt[4] = c1.x; cnt[5] = c1.y; cnt[6] = c1.z; cnt[7] = c1.w;
    }

    float nsum = 0.0f, H = 0.0f;
    int   tsum = 0;
#pragma unroll
    for (int j = 0; j < 8; ++j) {
        const float cf = cnt[j];
        const float nn = Nin[base + j] * 0.99f + 0.01f * cf;
        out[O_NN + base + j] = nn;
        nsum += nn;
        const float p = cf * (1.0f / 32768.0f);
        H += p * logf(p + 1e-10f);
        tsum += (int)cf;
    }

    // wave-inclusive scan of tsum
    int inc = tsum;
#pragma unroll
    for (int off = 1; off < 64; off <<= 1) {
        const int v = __shfl_up(inc, off, 64);
        if ((tid & 63) >= off) inc += v;
    }
    const int wv = tid >> 6, ln = tid & 63;
    if (ln == 63) wsum[wv] = inc;

#pragma unroll
    for (int off = 32; off; off >>= 1) {
        nsum += __shfl_down(nsum, off);
        H    += __shfl_down(H, off);
    }
    if (ln == 0) { r1[wv] = nsum; r2[wv] = H; }
    __syncthreads();

    int wbase = 0;
    for (int q = 0; q < wv; ++q) wbase += wsum[q];
    int run = wbase + inc - tsum;                    // exclusive prefix for base
    int* offp = (int*)ws + WS_OFF;
    int* curp = (int*)ws + WS_CUR;
#pragma unroll
    for (int j = 0; j < 8; ++j) {
        offp[base + j] = run;
        curp[base + j] = run;
        run += (int)cnt[j];
    }

    if (tid == 0) {
        const float nt = r1[0] + r1[1] + r1[2] + r1[3];
        const float Ht = r2[0] + r2[1] + r2[2] + r2[3];
        ws[WS_N] = nt;
        out[O_PERP] = expf(-Ht);
        out[O_LOSS] = 0.25f * ws[WS_LOSS] * (1.0f / 8388608.0f);
    }
}

// ---- counting-sort scatter: token ids + codes grouped by code ----
__global__ void k_scatter(float* __restrict__ ws) {
    const int t    = blockIdx.x * 256 + threadIdx.x;
    const int code = ((const int*)ws)[WS_IDX + t];
    const int slot = atomicAdd((int*)ws + WS_CUR + code, 1);
    ((int*)ws)[WS_SORT  + slot] = t;
    ((int*)ws)[WS_SCODE + slot] = code;
}

// ---- segmented reduction over sorted tokens: run-aggregated ESUM atomics ----
__global__ __launch_bounds__(256) void k_gather(float* __restrict__ ws) {
    __shared__ int stok[64], scod[64];
    const int g = blockIdx.x, tid = threadIdx.x, c = tid;
    if (tid < 64) {
        stok[tid] = ((const int*)ws)[WS_SORT  + g * 64 + tid];
        scod[tid] = ((const int*)ws)[WS_SCODE + g * 64 + tid];
    }
    __syncthreads();

    const _Float16* xh = (const _Float16*)(ws + WS_XH);
    float* esum = ws + WS_ESUM;

    float acc = 0.0f;
    for (int k0 = 0; k0 < 64; k0 += 8) {
        float v[8];
#pragma unroll
        for (int j = 0; j < 8; ++j)
            v[j] = (float)xh[(size_t)stok[k0 + j] * CDIM + c];
#pragma unroll
        for (int j = 0; j < 8; ++j) {
            const int k = k0 + j;
            acc += v[j];
            if (k == 63 || scod[k] != scod[k + 1]) {
                atomicAdd(&esum[(size_t)scod[k] * CDIM + c], acc);
                acc = 0.0f;
            }
        }
    }
}

// ---- EMA update from ESUM (coalesced, trivial) ----
__global__ __launch_bounds__(256) void k_update(
    const float* __restrict__ zavg, const float* __restrict__ krand,
    const float* __restrict__ ws, float* __restrict__ out)
{
    const int i = blockIdx.x, c = threadIdx.x;
    const float nn  = out[O_NN + i];
    const float n   = ws[WS_N];
    const float wgt = (nn + 1e-7f) / (n + NCODES * 1e-7f) * n;
    const size_t o  = (size_t)i * CDIM + c;
    const float ez  = 0.99f * zavg[o] + 0.01f * ws[WS_ESUM + o];
    out[O_ZAVG + o] = ez;
    out[O_EMB + o]  = (nn >= 1.0f) ? (ez / wgt) : krand[o];
}

extern "C" void kernel_launch(void* const* d_in, const int* in_sizes, int n_in,
                              void* d_out, int out_size, void* d_ws, size_t ws_size,
                              hipStream_t stream) {
    const float* z     = (const float*)d_in[0];
    const float* emb   = (const float*)d_in[1];
    const float* Nin   = (const float*)d_in[2];
    const float* zavg  = (const float*)d_in[3];
    const float* krand = (const float*)d_in[4];
    float* out = (float*)d_out;
    float* ws  = (float*)d_ws;

    // zero counts + loss + N + ESUM each call (one contiguous region)
    hipMemsetAsync(ws + WS_COUNTS, 0,
                   (size_t)(2048 + 4 + NCODES * CDIM) * sizeof(float), stream);

    k_ecvt    <<<NCODES / 8,  256, 0, stream>>>(emb, ws);
    k_main    <<<1024,        128, 0, stream>>>(z, ws);
    k_epi     <<<1024,        256, 0, stream>>>(z, emb, ws, out);
    k_finalize<<<1,           256, 0, stream>>>(Nin, ws, out);
    k_scatter <<<NTOK / 256,  256, 0, stream>>>(ws);
    k_gather  <<<NTOK / 64,   256, 0, stream>>>(ws);
    k_update  <<<NCODES,      256, 0, stream>>>(zavg, krand, ws, out);
}

// Round 11
// 135.337 us; speedup vs baseline: 1.0359x; 1.0207x over previous
//
#include <hip/hip_runtime.h>
#include <math.h>

// Problem constants
#define NCODES 2048
#define CDIM   256
#define SPAT   4096            // T*H*W
#define NTOK   32768
#define XSTR   260             // fp32 Xs row stride in k_epi (1040B, 16B-aligned)
#define EPI_TOK 32             // tokens per k_epi block (33.3KB Xs -> 4 blocks/CU, full-line IO)

// k_main geometry: 2048 blocks x 64 threads (1 wave) =
//   1024 token-groups(32 tok) x 2 code-halves. NO LDS, NO barriers.
#define ETILE    32            // codes per logical tile (fold granularity)
#define HALFCODE 1024
#define NTILES   (HALFCODE / ETILE)   // 32
#define HALFBYTES 524288       // 1024 codes x 512 B fp16 image per half

typedef _Float16 half8  __attribute__((ext_vector_type(8)));
typedef float    f32x4  __attribute__((ext_vector_type(4)));

// ws layout (float offsets)
#define WS_ENORM  0         // 2048
#define WS_COUNTS 2048      // 2048
#define WS_LOSS   4096
#define WS_N      4097
#define WS_ESUM   4100      // 2048*256 floats (memset with counts: [2048, 528388))
#define WS_IDX    528388    // int[32768] token -> code
#define WS_OFF    561156    // int[2048] exclusive-scan offsets
#define WS_CUR    563204    // int[2048] scatter cursors
#define WS_SORT   565252    // int[32768] token ids sorted by code
#define WS_SCODE  598020    // int[32768] code per sorted slot
#define WS_CAND   630788    // 16B-aligned; 32768 tok x 8 ushort
#define WS_E16    761860    // 16B-aligned; fp16 FRAGMENT-ORDER codebook image (1 MB)
#define WS_XH     1024004   // 16B-aligned; fp16 token-major z image (16.8 MB)

// d_out layout (float offsets)
#define O_QUANT 0
#define O_ENC   8388608
#define O_LOSS  8421376
#define O_PERP  8421377
#define O_EMB   8421378
#define O_NN    8945666
#define O_ZAVG  8947714

__device__ inline unsigned umn(unsigned a, unsigned b) { return a < b ? a : b; }
__device__ inline unsigned umx(unsigned a, unsigned b) { return a > b ? a : b; }
__device__ inline unsigned shflx16(unsigned v, int off) {
    return (unsigned)__shfl_xor((int)v, off, 16);
}

// ---- codebook prep: fp16 FRAGMENT-ORDER image + row norms (once per call) ----
// Image layout (bytes within a half):
//   offset = ((step*2 + j)*64 + lane)*16, step = tile*8 + ks, lane = lg*16 + lr.
// Lane (lg,lr)'s half8 = channels ks*32 + lg*8 .. +8 of code tile*32 + j*16 + lr.
// k_main loads it as one coalesced global b128 per (step, j): base+step*2048+j*1024+l*16.
__global__ void k_ecvt(const float* __restrict__ emb, float* __restrict__ ws) {
    const int tid  = threadIdx.x;
    const int code = (blockIdx.x << 3) + (tid >> 5);   // 8 codes/block
    const int cg   = tid & 31;                         // c = cg*8
    const float* src = emb + (size_t)code * CDIM + (cg << 3);
    const float4 f0 = *(const float4*)src;
    const float4 f1 = *(const float4*)(src + 4);
    half8 h = { (_Float16)f0.x, (_Float16)f0.y, (_Float16)f0.z, (_Float16)f0.w,
                (_Float16)f1.x, (_Float16)f1.y, (_Float16)f1.z, (_Float16)f1.w };
    const int half = code >> 10;
    const int cih  = code & 1023;
    const int tile = cih >> 5;
    const int j    = (cih >> 4) & 1;
    const int lr   = cih & 15;
    const int ks   = cg >> 2;
    const int lg   = cg & 3;
    char* dst = (char*)(ws + WS_E16) + (size_t)half * HALFBYTES
              + (size_t)((((tile * 8 + ks) * 2 + j) * 64) + (lg * 16 + lr)) * 16;
    *(half8*)dst = h;
    float s = f0.x * f0.x + f0.y * f0.y + f0.z * f0.z + f0.w * f0.w
            + f1.x * f1.x + f1.y * f1.y + f1.z * f1.z + f1.w * f1.w;
#pragma unroll
    for (int off = 16; off; off >>= 1) s += __shfl_down(s, off, 32);
    if (cg == 0) ws[WS_ENORM + code] = s;   // exact norm (k_epi re-rank uses it)
}

// ---------------- MFMA distance + top-4-per-half candidate kernel ----------------
// 2048 blocks x 64 threads (1 wave). Block = (32 tokens) x (code-half of 1024).
// LDS-FREE: B-fragments load straight from the fragment-order L2-resident image
// (coalesced b128 per step), depth-2 register prefetch; compiler tracks the
// register deps with counted vmcnt -> no barriers, no vmcnt(0) drains, no LDS
// pipe traffic (the old structure spent ~20us/CU on ds_read_b128 + barriers).
// XCD pair-swizzle: both halves of a token group land on one XCD (z L2-paired).
// ch==0 waves also dump their fp16 A-frags as the token-major Xh image.
__global__ __launch_bounds__(64, 2) void k_main(
    const float* __restrict__ z, float* __restrict__ ws)
{
    const int l   = threadIdx.x;               // lane 0..63
    const int raw = blockIdx.x;
    const int xcd = raw & 7, sub = raw >> 3;   // 2048 = 8 XCDs x 256 subs
    const int tb  = xcd * 128 + (sub >> 1);    // token group 0..1023 (32 tokens)
    const int ch  = sub & 1;                   // code half
    const int b   = tb >> 7;                   // batch 0..7
    const int s0  = (tb & 127) * 32;
    const float* zb = z + (size_t)b * CDIM * SPAT + s0;
    const char* eimg = (const char*)(ws + WS_E16) + (size_t)ch * HALFBYTES;

    const int lr = l & 15, lg = l >> 4;

    // ---- preload B frags for steps 0 and 1 (issued before everything) ----
    half8 c0 = *(const half8*)(eimg + 0 * 1024 + l * 16);
    half8 c1 = *(const half8*)(eimg + 1 * 1024 + l * 16);
    half8 d0 = *(const half8*)(eimg + 2 * 1024 + l * 16);
    half8 d1 = *(const half8*)(eimg + 3 * 1024 + l * 16);

    // ---- A-frags: 2 sets x 8 ks, global -> registers ----
    half8 a[2][8];
#pragma unroll
    for (int as = 0; as < 2; ++as)
#pragma unroll
    for (int ks = 0; ks < 8; ++ks) {
        float v[8];
#pragma unroll
        for (int e = 0; e < 8; ++e)
            v[e] = zb[(size_t)(ks * 32 + lg * 8 + e) * SPAT + (as * 16 + lr)];
        half8 h = { (_Float16)v[0], (_Float16)v[1], (_Float16)v[2], (_Float16)v[3],
                    (_Float16)v[4], (_Float16)v[5], (_Float16)v[6], (_Float16)v[7] };
        a[as][ks] = h;
    }

    // ---- Xh dump (ch==0 waves only): token-major fp16 rows from A-frags ----
    if (ch == 0) {
        _Float16* xh = (_Float16*)(ws + WS_XH);
#pragma unroll
        for (int as = 0; as < 2; ++as) {
            _Float16* xr = xh + (size_t)(b * SPAT + s0 + as * 16 + lr) * CDIM;
#pragma unroll
            for (int ks = 0; ks < 8; ++ks)
                *(half8*)(xr + ks * 32 + lg * 8) = a[as][ks];
        }
    }

    unsigned kb0[2][4], kb1[2][4];   // top-2 packed keys per (A-set, r) slot
#pragma unroll
    for (int as = 0; as < 2; ++as)
#pragma unroll
    for (int r = 0; r < 4; ++r) { kb0[as][r] = 0xFFFFFFFFu; kb1[as][r] = 0xFFFFFFFFu; }

    for (int tile = 0; tile < NTILES; ++tile) {
        // e-norms issued at tile start: older than all later B loads, so the
        // fold's use never forces an extra wait (in-order vmcnt retirement).
        const float en0 = ws[WS_ENORM + ch * HALFCODE + tile * ETILE + lr];
        const float en1 = ws[WS_ENORM + ch * HALFCODE + tile * ETILE + 16 + lr];

        f32x4 acc[2][2];
#pragma unroll
        for (int as = 0; as < 2; ++as)
#pragma unroll
        for (int j = 0; j < 2; ++j) acc[as][j] = (f32x4)0.0f;

#pragma unroll
        for (int ks = 0; ks < 8; ++ks) {
            const int step = tile * 8 + ks;
            half8 n0, n1;
            if (step + 2 < 256) {
                const char* p = eimg + (size_t)(step + 2) * 2048 + l * 16;
                n0 = *(const half8*)p;
                n1 = *(const half8*)(p + 1024);
            }
            __builtin_amdgcn_s_setprio(1);
#pragma unroll
            for (int as = 0; as < 2; ++as) {
                acc[as][0] = __builtin_amdgcn_mfma_f32_16x16x32_f16(
                    a[as][ks], c0, acc[as][0], 0, 0, 0);
                acc[as][1] = __builtin_amdgcn_mfma_f32_16x16x32_f16(
                    a[as][ks], c1, acc[as][1], 0, 0, 0);
            }
            __builtin_amdgcn_s_setprio(0);
            c0 = d0; c1 = d1;
            if (step + 2 < 256) { d0 = n0; d1 = n1; }
        }

        // ---- fold into per-lane top-2 packed keys (5 VALU per value) ----
        const float enb0 = en0 + 4096.0f;
        const float enb1 = en1 + 4096.0f;
        const unsigned code0 = (unsigned)(ch * HALFCODE + tile * ETILE + lr);
        const unsigned code1 = code0 + 16u;
#pragma unroll
        for (int as = 0; as < 2; ++as)
#pragma unroll
        for (int r = 0; r < 4; ++r) {
            {
                const float d = fmaf(acc[as][0][r], -2.0f, enb0);
                const unsigned key = (__float_as_uint(d) & 0xFFFFF800u) | code0;
                const unsigned hi = umx(kb0[as][r], key);
                kb0[as][r] = umn(kb0[as][r], key);
                kb1[as][r] = umn(kb1[as][r], hi);
            }
            {
                const float d = fmaf(acc[as][1][r], -2.0f, enb1);
                const unsigned key = (__float_as_uint(d) & 0xFFFFF800u) | code1;
                const unsigned hi = umx(kb0[as][r], key);
                kb0[as][r] = umn(kb0[as][r], key);
                kb1[as][r] = umn(kb1[as][r], hi);
            }
        }
    }

    // ---- 16-lane bitonic merge of sorted-4 key lists -> top-4 per token ----
#pragma unroll
    for (int as = 0; as < 2; ++as)
#pragma unroll
    for (int r = 0; r < 4; ++r) {
        unsigned k0 = kb0[as][r], k1 = kb1[as][r];
        unsigned k2 = 0xFFFFFFFFu, k3 = 0xFFFFFFFFu;
#pragma unroll
        for (int off = 8; off; off >>= 1) {
            const unsigned o0 = shflx16(k0, off);
            const unsigned o1 = shflx16(k1, off);
            const unsigned o2 = shflx16(k2, off);
            const unsigned o3 = shflx16(k3, off);
            // lowest-4 of two ascending 4-lists: min with reversed other -> bitonic
            const unsigned m0 = umn(k0, o3), m1 = umn(k1, o2);
            const unsigned m2 = umn(k2, o1), m3 = umn(k3, o0);
            // sort the bitonic 4-sequence
            const unsigned t0 = umn(m0, m2), t2 = umx(m0, m2);
            const unsigned t1 = umn(m1, m3), t3 = umx(m1, m3);
            k0 = umn(t0, t1); k1 = umx(t0, t1);
            k2 = umn(t2, t3); k3 = umx(t2, t3);
        }
        if (lr == 0) {
            const int tokg = b * SPAT + s0 + as * 16 + lg * 4 + r;
            ushort4 c4;
            c4.x = (unsigned short)(k0 & 2047u);
            c4.y = (unsigned short)(k1 & 2047u);
            c4.z = (unsigned short)(k2 & 2047u);
            c4.w = (unsigned short)(k3 & 2047u);
            *(ushort4*)((unsigned short*)((int*)ws + WS_CAND) + (size_t)tokg * 8 + ch * 4) = c4;
        }
    }
}

// ---------------- exact fp32 re-rank (8 cands) + epilogue ----------------
// 1024 blocks x 256 threads, 32 tokens/block, Xs 33.3KB -> 4 blocks/CU.
// EPI_TOK=32 => 128B full-line z reads and quant writes.
__global__ __launch_bounds__(256, 4) void k_epi(
    const float* __restrict__ z, const float* __restrict__ emb,
    float* __restrict__ ws, float* __restrict__ out)
{
    __shared__ float Xs[EPI_TOK * XSTR];   // 33280 B fp32
    __shared__ int   idxs[EPI_TOK];
    __shared__ float lloss[EPI_TOK];

    const int tid = threadIdx.x, blk = blockIdx.x;
    const int b   = blk >> 7;              // 8 batches x 128 s-groups
    const int s0  = (blk & 127) * EPI_TOK;
    const float* zb = z + (size_t)b * CDIM * SPAT + s0;

    // ---- stage X tile fp32 (coalesced over s; 32 s x 4B = full lines) ----
    {
        const int s  = tid & 31;
        const int c0 = tid >> 5;   // 0..7
#pragma unroll 4
        for (int c = c0; c < CDIM; c += 8)
            Xs[s * XSTR + c] = zb[(size_t)c * SPAT + s];
    }
    __syncthreads();

    // ---- exact re-rank: 8 threads/token, all-cand partials per 32-ch slice ----
    {
        const int t = tid >> 3, h = tid & 7;
        const unsigned short* cp =
            (const unsigned short*)((int*)ws + WS_CAND) + ((size_t)blk * EPI_TOK + t) * 8;
        const int mycand = cp[h];
        const float en_h = ws[WS_ENORM + mycand];   // hoisted: hides under dots

        int cand[8];
        {
            const ushort4 ca = *(const ushort4*)cp;
            const ushort4 cb = *(const ushort4*)(cp + 4);
            cand[0] = ca.x; cand[1] = ca.y; cand[2] = ca.z; cand[3] = ca.w;
            cand[4] = cb.x; cand[5] = cb.y; cand[6] = cb.z; cand[7] = cb.w;
        }

        // x channel slice: 8 float4 at c = h*4 + q*32 (bank-spread by h*4)
        float4 xq[8];
#pragma unroll
        for (int q = 0; q < 8; ++q)
            xq[q] = *(const float4*)&Xs[t * XSTR + q * 32 + h * 4];

        float xn = 0.0f;   // ||x||^2 partial (for loss)
#pragma unroll
        for (int q = 0; q < 8; ++q)
            xn += xq[q].x * xq[q].x + xq[q].y * xq[q].y
                + xq[q].z * xq[q].z + xq[q].w * xq[q].w;
        xn += __shfl_xor(xn, 1, 8);
        xn += __shfl_xor(xn, 2, 8);
        xn += __shfl_xor(xn, 4, 8);   // xn now = full ||x||^2 on all 8 lanes

        float p8[8];
#pragma unroll
        for (int k = 0; k < 8; ++k) {
            const float* er = emb + (size_t)cand[k] * CDIM + h * 4;
            float dp = 0.0f;
#pragma unroll
            for (int q = 0; q < 8; ++q) {
                const float4 e4 = *(const float4*)(er + q * 32);
                dp += xq[q].x * e4.x + xq[q].y * e4.y + xq[q].z * e4.z + xq[q].w * e4.w;
            }
            p8[k] = dp;
        }

        // paired butterfly: lane h ends with full dot of cand h (width 8)
        float np4[4];
#pragma unroll
        for (int k2 = 0; k2 < 4; ++k2) {
            const float own = (h & 1) ? p8[2 * k2 + 1] : p8[2 * k2];
            const float snd = (h & 1) ? p8[2 * k2]     : p8[2 * k2 + 1];
            np4[k2] = own + __shfl_xor(snd, 1, 8);
        }
        float nq2[2];
#pragma unroll
        for (int k3 = 0; k3 < 2; ++k3) {
            const float own = ((h >> 1) & 1) ? np4[2 * k3 + 1] : np4[2 * k3];
            const float snd = ((h >> 1) & 1) ? np4[2 * k3]     : np4[2 * k3 + 1];
            nq2[k3] = own + __shfl_xor(snd, 2, 8);
        }
        const float own = ((h >> 2) & 1) ? nq2[1] : nq2[0];
        const float snd = ((h >> 2) & 1) ? nq2[0] : nq2[1];
        const float dot = own + __shfl_xor(snd, 4, 8);

        // exact fp32 compare, code tie-break (matches reference argmin)
        float bd = en_h - 2.0f * dot;
        int   bi = mycand;
#pragma unroll
        for (int off = 4; off; off >>= 1) {
            const float od = __shfl_xor(bd, off, 8);
            const int   oi = __shfl_xor(bi, off, 8);
            if (od < bd || (od == bd && oi < bi)) { bd = od; bi = oi; }
        }
        if (h == 0) {
            idxs[t]  = bi;
            lloss[t] = xn + bd;                      // sum((x-e)^2) = ||x||^2 + d_win
            out[O_ENC + blk * EPI_TOK + t] = (float)bi;
            ((int*)ws)[WS_IDX + blk * EPI_TOK + t] = bi;
            atomicAdd(ws + WS_COUNTS + bi, 1.0f);
        }
    }
    __syncthreads();

    // ---- e-fill: overwrite Xs with winner rows (coalesced 128B/token-chunk) ----
    {
        const int t = tid >> 3, h = tid & 7;
        const float* ewin = emb + (size_t)idxs[t] * CDIM + h * 4;
#pragma unroll
        for (int q = 0; q < 8; ++q)
            *(float4*)&Xs[t * XSTR + q * 32 + h * 4] = *(const float4*)(ewin + q * 32);
    }
    __syncthreads();

    // ---- pure quant column write (coalesced over s; full 128B lines) ----
    {
        const int s  = tid & 31;
        const int c0 = tid >> 5;
        float* qcol = out + O_QUANT + (size_t)b * CDIM * SPAT + s0 + s;
#pragma unroll 4
        for (int c = c0; c < CDIM; c += 8)
            qcol[(size_t)c * SPAT] = Xs[s * XSTR + c];
    }
    if (tid == 0) {
        float ls = 0.0f;
#pragma unroll
        for (int t = 0; t < EPI_TOK; ++t) ls += lloss[t];
        atomicAdd(ws + WS_LOSS, ls);
    }
}

// ---- finalize: new_N / perplexity / loss  +  exclusive scan of counts ----
__global__ void k_finalize(const float* __restrict__ Nin, float* __restrict__ ws,
                           float* __restrict__ out) {
    __shared__ float r1[4], r2[4];
    __shared__ int   wsum[4];
    const int tid  = threadIdx.x;
    const int base = tid * 8;                       // contiguous 8 codes/thread

    float cnt[8];
    {
        const float4 c0 = *(const float4*)(ws + WS_COUNTS + base);
        const float4 c1 = *(const float4*)(ws + WS_COUNTS + base + 4);
        cnt[0] = c0.x; cnt[1] = c0.y; cnt[2] = c0.z; cnt[3] = c0.w;
        cnt[4] = c1.x; cnt[5] = c1.y; cnt[6] = c1.z; cnt[7] = c1.w;
    }

    float nsum = 0.0f, H = 0.0f;
    int   tsum = 0;
#pragma unroll
    for (int j = 0; j < 8; ++j) {
        const float cf = cnt[j];
        const float nn = Nin[base + j] * 0.99f + 0.01f * cf;
        out[O_NN + base + j] = nn;
        nsum += nn;
        const float p = cf * (1.0f / 32768.0f);
        H += p * logf(p + 1e-10f);
        tsum += (int)cf;
    }

    // wave-inclusive scan of tsum
    int inc = tsum;
#pragma unroll
    for (int off = 1; off < 64; off <<= 1) {
        const int v = __shfl_up(inc, off, 64);
        if ((tid & 63) >= off) inc += v;
    }
    const int wv = tid >> 6, ln = tid & 63;
    if (ln == 63) wsum[wv] = inc;

#pragma unroll
    for (int off = 32; off; off >>= 1) {
        nsum += __shfl_down(nsum, off);
        H    += __shfl_down(H, off);
    }
    if (ln == 0) { r1[wv] = nsum; r2[wv] = H; }
    __syncthreads();

    int wbase = 0;
    for (int q = 0; q < wv; ++q) wbase += wsum[q];
    int run = wbase + inc - tsum;                    // exclusive prefix for base
    int* offp = (int*)ws + WS_OFF;
    int* curp = (int*)ws + WS_CUR;
#pragma unroll
    for (int j = 0; j < 8; ++j) {
        offp[base + j] = run;
        curp[base + j] = run;
        run += (int)cnt[j];
    }

    if (tid == 0) {
        const float nt = r1[0] + r1[1] + r1[2] + r1[3];
        const float Ht = r2[0] + r2[1] + r2[2] + r2[3];
        ws[WS_N] = nt;
        out[O_PERP] = expf(-Ht);
        out[O_LOSS] = 0.25f * ws[WS_LOSS] * (1.0f / 8388608.0f);
    }
}

// ---- counting-sort scatter: token ids + codes grouped by code ----
__global__ void k_scatter(float* __restrict__ ws) {
    const int t    = blockIdx.x * 256 + threadIdx.x;
    const int code = ((const int*)ws)[WS_IDX + t];
    const int slot = atomicAdd((int*)ws + WS_CUR + code, 1);
    ((int*)ws)[WS_SORT  + slot] = t;
    ((int*)ws)[WS_SCODE + slot] = code;
}

// ---- segmented reduction over sorted tokens: run-aggregated ESUM atomics ----
__global__ __launch_bounds__(256) void k_gather(float* __restrict__ ws) {
    __shared__ int stok[64], scod[64];
    const int g = blockIdx.x, tid = threadIdx.x, c = tid;
    if (tid < 64) {
        stok[tid] = ((const int*)ws)[WS_SORT  + g * 64 + tid];
        scod[tid] = ((const int*)ws)[WS_SCODE + g * 64 + tid];
    }
    __syncthreads();

    const _Float16* xh = (const _Float16*)(ws + WS_XH);
    float* esum = ws + WS_ESUM;

    float acc = 0.0f;
    for (int k0 = 0; k0 < 64; k0 += 8) {
        float v[8];
#pragma unroll
        for (int j = 0; j < 8; ++j)
            v[j] = (float)xh[(size_t)stok[k0 + j] * CDIM + c];
#pragma unroll
        for (int j = 0; j < 8; ++j) {
            const int k = k0 + j;
            acc += v[j];
            if (k == 63 || scod[k] != scod[k + 1]) {
                atomicAdd(&esum[(size_t)scod[k] * CDIM + c], acc);
                acc = 0.0f;
            }
        }
    }
}

// ---- EMA update from ESUM (coalesced, trivial) ----
__global__ __launch_bounds__(256) void k_update(
    const float* __restrict__ zavg, const float* __restrict__ krand,
    const float* __restrict__ ws, float* __restrict__ out)
{
    const int i = blockIdx.x, c = threadIdx.x;
    const float nn  = out[O_NN + i];
    const float n   = ws[WS_N];
    const float wgt = (nn + 1e-7f) / (n + NCODES * 1e-7f) * n;
    const size_t o  = (size_t)i * CDIM + c;
    const float ez  = 0.99f * zavg[o] + 0.01f * ws[WS_ESUM + o];
    out[O_ZAVG + o] = ez;
    out[O_EMB + o]  = (nn >= 1.0f) ? (ez / wgt) : krand[o];
}

extern "C" void kernel_launch(void* const* d_in, const int* in_sizes, int n_in,
                              void* d_out, int out_size, void* d_ws, size_t ws_size,
                              hipStream_t stream) {
    const float* z     = (const float*)d_in[0];
    const float* emb   = (const float*)d_in[1];
    const float* Nin   = (const float*)d_in[2];
    const float* zavg  = (const float*)d_in[3];
    const float* krand = (const float*)d_in[4];
    float* out = (float*)d_out;
    float* ws  = (float*)d_ws;

    // zero counts + loss + N + ESUM each call (one contiguous region)
    hipMemsetAsync(ws + WS_COUNTS, 0,
                   (size_t)(2048 + 4 + NCODES * CDIM) * sizeof(float), stream);

    k_ecvt    <<<NCODES / 8,  256, 0, stream>>>(emb, ws);
    k_main    <<<2048,        64,  0, stream>>>(z, ws);
    k_epi     <<<1024,        256, 0, stream>>>(z, emb, ws, out);
    k_finalize<<<1,           256, 0, stream>>>(Nin, ws, out);
    k_scatter <<<NTOK / 256,  256, 0, stream>>>(ws);
    k_gather  <<<NTOK / 64,   256, 0, stream>>>(ws);
    k_update  <<<NCODES,      256, 0, stream>>>(zavg, krand, ws, out);
}